// Round 11
// baseline (3067.411 us; speedup 1.0000x reference)
//
#include <hip/hip_runtime.h>
#include <hip/hip_fp16.h>
#include <math.h>

// Problem constants
static constexpr int BB = 64, TT = 26, EE = 300, HH = 1024;
static constexpr int FEAT = 2048, SS = 49;
static constexpr int D1 = 245000, D2 = 5000;
static constexpr int MOUT = 1000;
static constexpr int VOCAB = 3000;

static constexpr int UPAD = 1008;                // u-dim padded: 1000 + 8 wrap rows
static constexpr int FOLD_R = 16000;             // v6 proven config
static constexpr int FOLD_NR = 16;
static constexpr int BCAP = 8192;                // bucket capacity (mean 6634)
static constexpr int NITEMS = FEAT * SS;         // 100352

// ---------------------------------------------------------------------------
// Generic fp32 GEMM: C[M,N] = act( A(M,K) * B(N,K)^T + bias1 + bias2 )
// ---------------------------------------------------------------------------
template <int BM, int BN, int BK, int TM, int TN, bool RELU>
__global__ void gemm_abt(const float* __restrict__ A, const float* __restrict__ B,
                         const float* __restrict__ bias1, const float* __restrict__ bias2,
                         float* __restrict__ C,
                         int M, int N, int K, int lda, int ldb, int ldc) {
    constexpr int THREADS = (BM / TM) * (BN / TN);
    __shared__ __align__(16) float As[BK][BM + 4];
    __shared__ __align__(16) float Bs[BK][BN + 4];
    const int tid = threadIdx.x;
    const int tx = tid % (BN / TN);
    const int ty = tid / (BN / TN);
    const int block_m = blockIdx.y * BM;
    const int block_n = blockIdx.x * BN;
    float acc[TM][TN];
#pragma unroll
    for (int i = 0; i < TM; i++)
#pragma unroll
        for (int j = 0; j < TN; j++) acc[i][j] = 0.f;

    for (int k0 = 0; k0 < K; k0 += BK) {
        for (int i = tid; i < BM * BK; i += THREADS) {
            int m = i / BK, kk = i % BK;
            int gm = block_m + m, gk = k0 + kk;
            As[kk][m] = (gm < M && gk < K) ? A[(size_t)gm * lda + gk] : 0.f;
        }
        for (int i = tid; i < BN * BK; i += THREADS) {
            int n = i / BK, kk = i % BK;
            int gn = block_n + n, gk = k0 + kk;
            Bs[kk][n] = (gn < N && gk < K) ? B[(size_t)gn * ldb + gk] : 0.f;
        }
        __syncthreads();
#pragma unroll
        for (int kk = 0; kk < BK; kk++) {
            float a[TM], b[TN];
            if constexpr ((TM & 3) == 0 && (TN & 3) == 0) {
#pragma unroll
                for (int i = 0; i < TM / 4; i++) {
                    float4 t4 = *reinterpret_cast<const float4*>(&As[kk][ty * TM + 4 * i]);
                    a[4 * i] = t4.x; a[4 * i + 1] = t4.y;
                    a[4 * i + 2] = t4.z; a[4 * i + 3] = t4.w;
                }
#pragma unroll
                for (int j = 0; j < TN / 4; j++) {
                    float4 t4 = *reinterpret_cast<const float4*>(&Bs[kk][tx * TN + 4 * j]);
                    b[4 * j] = t4.x; b[4 * j + 1] = t4.y;
                    b[4 * j + 2] = t4.z; b[4 * j + 3] = t4.w;
                }
            } else {
#pragma unroll
                for (int i = 0; i < TM; i++) a[i] = As[kk][ty * TM + i];
#pragma unroll
                for (int j = 0; j < TN; j++) b[j] = Bs[kk][tx * TN + j];
            }
#pragma unroll
            for (int i = 0; i < TM; i++)
#pragma unroll
                for (int j = 0; j < TN; j++) acc[i][j] += a[i] * b[j];
        }
        __syncthreads();
    }
#pragma unroll
    for (int i = 0; i < TM; i++) {
        int gm = block_m + ty * TM + i;
        if (gm >= M) continue;
#pragma unroll
        for (int j = 0; j < TN; j++) {
            int gn = block_n + tx * TN + j;
            if (gn >= N) continue;
            float v = acc[i][j];
            if (bias1) v += bias1[gn];
            if (bias2) v += bias2[gn];
            if (RELU) v = fmaxf(v, 0.f);
            C[(size_t)gm * ldc + gn] = v;
        }
    }
}

// ---------------------------------------------------------------------------
// xw transpose: xw[(b*T+t), g] -> xwT[(t*4096+g)*64 + b]
// ---------------------------------------------------------------------------
__global__ void xwt_transpose(const float* __restrict__ xw, float* __restrict__ xwT) {
    __shared__ float L[64][65];
    const int t = blockIdx.x;
    const int g0 = blockIdx.y * 64;
    const int tid = threadIdx.x;
    for (int u = 0; u < 16; u++) {
        int idx = u * 256 + tid;
        int b = idx >> 6, g = idx & 63;
        L[g][b] = xw[((size_t)b * TT + t) * 4096 + g0 + g];
    }
    __syncthreads();
    for (int u = 0; u < 16; u++) {
        int idx = u * 256 + tid;
        int g = idx >> 6, b = idx & 63;
        xwT[((size_t)t * 4096 + g0 + g) * 64 + b] = L[g][b];
    }
}

// ---------------------------------------------------------------------------
// LSTM per-step kernel v5.  v4's blocking was 1 W-row x 4 b per thread = 5
// ds_read_b128 per 16 FMA (1280 b128/thread/step -> ~17 us/step LDS-BW
// bound).  v5: thread = (k-quarter kq, gate rq, b4) computing 4 rows x 4
// cols over its k-quarter: per k = 4 ds_read_b32 W (2-way bank: rq*528 mod
// 32 = {0,16}) + 1 ds_read_b128 h (2-way) + 16 FMA -> ~6.8 us/step.
// kq partials reduced via 16 KB LDS aliasing the W buffer (post-sync).
// 256 blocks x 256 thr; LDS ~81 KB (1 block/CU, 4 waves).
// ---------------------------------------------------------------------------
__global__ void __launch_bounds__(256)
lstm_step5(const float* __restrict__ xwT, const float* __restrict__ W_hh,
           const float* __restrict__ hin, float* __restrict__ hout,
           float* __restrict__ cst, float* __restrict__ hs, int step) {
    __shared__ __align__(16) float hch[2][128][64];   // 64 KB
    __shared__ __align__(16) float wch[2][16][132];   // 16.9 KB (pad 132: W-read 2-way)
    const int tid = threadIdx.x;
    const int hh0 = blockIdx.x * 4;
    float* red = (float*)wch;                         // 16 KB reduce buf (post-sync alias)

    if (step > 0) {
        const int kq = tid >> 6;                      // wave = k-quarter
        const int rq = (tid >> 4) & 3;                // gate
        const int b4 = tid & 15;                      // b quad
        float acc[4][4];
#pragma unroll
        for (int i = 0; i < 4; i++)
#pragma unroll
            for (int j = 0; j < 4; j++) acc[i][j] = 0.f;
        // stage chunk 0
        {
            const float4* hsrc = (const float4*)hin;
            float4* hdst = (float4*)hch[0];
#pragma unroll
            for (int u = 0; u < 8; u++) hdst[tid + 256 * u] = hsrc[tid + 256 * u];
#pragma unroll
            for (int u = 0; u < 2; u++) {
                int f4 = tid + 256 * u;
                int r = f4 >> 5, c = f4 & 31;         // 32 float4 per W-row chunk
                float4 wv = *(const float4*)(
                    W_hh + ((size_t)((r >> 2) * 1024 + hh0 + (r & 3))) * 1024 + c * 4);
                *(float4*)&wch[0][r][c * 4] = wv;
            }
        }
        __syncthreads();
        for (int ck = 0; ck < 8; ck++) {
            const int cur = ck & 1;
            float4 hreg[8];
            float4 wreg[2];
            if (ck < 7) {
                const float4* hsrc = (const float4*)(hin + (ck + 1) * 8192);
#pragma unroll
                for (int u = 0; u < 8; u++) hreg[u] = hsrc[tid + 256 * u];
#pragma unroll
                for (int u = 0; u < 2; u++) {
                    int f4 = tid + 256 * u;
                    int r = f4 >> 5, c = f4 & 31;
                    wreg[u] = *(const float4*)(
                        W_hh + ((size_t)((r >> 2) * 1024 + hh0 + (r & 3))) * 1024 +
                        (ck + 1) * 128 + c * 4);
                }
            }
#pragma unroll 8
            for (int k = 0; k < 32; k++) {
                const int kk = kq * 32 + k;
                float w0 = wch[cur][rq * 4 + 0][kk];
                float w1 = wch[cur][rq * 4 + 1][kk];
                float w2 = wch[cur][rq * 4 + 2][kk];
                float w3 = wch[cur][rq * 4 + 3][kk];
                float4 hv = *(const float4*)&hch[cur][kk][b4 * 4];
                acc[0][0] = fmaf(w0, hv.x, acc[0][0]);
                acc[0][1] = fmaf(w0, hv.y, acc[0][1]);
                acc[0][2] = fmaf(w0, hv.z, acc[0][2]);
                acc[0][3] = fmaf(w0, hv.w, acc[0][3]);
                acc[1][0] = fmaf(w1, hv.x, acc[1][0]);
                acc[1][1] = fmaf(w1, hv.y, acc[1][1]);
                acc[1][2] = fmaf(w1, hv.z, acc[1][2]);
                acc[1][3] = fmaf(w1, hv.w, acc[1][3]);
                acc[2][0] = fmaf(w2, hv.x, acc[2][0]);
                acc[2][1] = fmaf(w2, hv.y, acc[2][1]);
                acc[2][2] = fmaf(w2, hv.z, acc[2][2]);
                acc[2][3] = fmaf(w2, hv.w, acc[2][3]);
                acc[3][0] = fmaf(w3, hv.x, acc[3][0]);
                acc[3][1] = fmaf(w3, hv.y, acc[3][1]);
                acc[3][2] = fmaf(w3, hv.z, acc[3][2]);
                acc[3][3] = fmaf(w3, hv.w, acc[3][3]);
            }
            if (ck < 7) {
                float4* hdst = (float4*)hch[cur ^ 1];
#pragma unroll
                for (int u = 0; u < 8; u++) hdst[tid + 256 * u] = hreg[u];
#pragma unroll
                for (int u = 0; u < 2; u++) {
                    int f4 = tid + 256 * u;
                    int r = f4 >> 5, c = f4 & 31;
                    *(float4*)&wch[cur ^ 1][r][c * 4] = wreg[u];
                }
            }
            __syncthreads();
        }
        // all compute done (post-sync): alias wch as red[row][b][kq]
#pragma unroll
        for (int i = 0; i < 4; i++)
#pragma unroll
            for (int j = 0; j < 4; j++)
                red[(((rq * 4 + i) * 64) + (b4 * 4 + j)) * 4 + kq] = acc[i][j];
        __syncthreads();
    }
    // tail: tid = i*64 + b  (4 hidden x 64 batch = 256 threads exactly)
    {
        const int i = tid >> 6;
        const int b = tid & 63;
        const int row = hh0 + i;
        const int idx = row * 64 + b;
        float g4[4];
#pragma unroll
        for (int j = 0; j < 4; j++) {
            float sum = xwT[((size_t)step * 4096 + j * 1024 + row) * 64 + b];
            if (step > 0) {
                float4 p = *(const float4*)&red[((j * 4 + i) * 64 + b) * 4];
                sum += (p.x + p.y) + (p.z + p.w);
            }
            g4[j] = sum;
        }
        float si = 1.f / (1.f + expf(-g4[0]));
        float sf = 1.f / (1.f + expf(-g4[1]));
        float tg = tanhf(g4[2]);
        float so = 1.f / (1.f + expf(-g4[3]));
        float cp = (step > 0) ? cst[idx] : 0.f;
        float cn = sf * cp + si * tg;
        cst[idx] = cn;
        float hn = so * tanhf(cn);
        hout[idx] = hn;
        hs[((size_t)step * BB + b) * HH + row] = hn;
    }
}

// Wave-per-row 512-dot: out[r] = dot(arow(r), wrow(g)) + b[g] (r8 proven).
__global__ void qa2_wave(const float* __restrict__ qa, const float* __restrict__ Wq2,
                         const float* __restrict__ bq2, float* __restrict__ out) {
    int wv = (blockIdx.x * blockDim.x + threadIdx.x) >> 6;
    int lane = threadIdx.x & 63;
    if (wv >= BB * 2 * TT) return;
    int t = wv % TT;
    int bg = wv / TT;
    int g = bg & 1;
    const float* arow = qa + ((size_t)t * BB + (bg >> 1)) * 512;
    const float* wrow = Wq2 + g * 512;
    float acc = 0.f;
#pragma unroll
    for (int o = 0; o < 8; o++) acc += wrow[lane + 64 * o] * arow[lane + 64 * o];
    for (int off = 32; off; off >>= 1) acc += __shfl_down(acc, off);
    if (lane == 0) out[wv] = acc + bq2[g];
}

__global__ void ia2_wave(const float* __restrict__ ia, const float* __restrict__ Wi2,
                         const float* __restrict__ bi2, float* __restrict__ out) {
    int wv = (blockIdx.x * blockDim.x + threadIdx.x) >> 6;
    int lane = threadIdx.x & 63;
    if (wv >= BB * 2 * SS) return;
    int s = wv % SS;
    int bg = wv / SS;
    int g = bg & 1;
    const float* arow = ia + ((size_t)(bg >> 1) * SS + s) * 512;
    const float* wrow = Wi2 + g * 512;
    float acc = 0.f;
#pragma unroll
    for (int o = 0; o < 8; o++) acc += wrow[lane + 64 * o] * arow[lane + 64 * o];
    for (int off = 32; off; off >>= 1) acc += __shfl_down(acc, off);
    if (lane == 0) out[wv] = acc + bi2[g];
}

// Wave-per-row softmax, len <= 64.
__global__ void softmax_wave(float* __restrict__ x, int rows, int len) {
    int wv = (blockIdx.x * blockDim.x + threadIdx.x) >> 6;
    int lane = threadIdx.x & 63;
    if (wv >= rows) return;
    float* xr = x + (size_t)wv * len;
    float v = (lane < len) ? xr[lane] : -1e30f;
    float m = v;
    for (int off = 32; off; off >>= 1) m = fmaxf(m, __shfl_xor(m, off));
    float e = (lane < len) ? expf(v - m) : 0.f;
    float ssum = e;
    for (int off = 32; off; off >>= 1) ssum += __shfl_xor(ssum, off);
    if (lane < len) xr[lane] = e / ssum;
}

__global__ void qfeat_kernel(const float* __restrict__ qatt, const float* __restrict__ hs,
                             float* __restrict__ qf) {
    int idx = blockIdx.x * blockDim.x + threadIdx.x;
    if (idx >= BB * 2048) return;
    int b = idx >> 11;
    int gh = idx & 2047;
    int g = gh >> 10;
    int hh = gh & 1023;
    float acc = 0.f;
    for (int t = 0; t < TT; t++)
        acc += qatt[((size_t)b * 2 + g) * TT + t] * hs[((size_t)t * BB + b) * HH + hh];
    qf[idx] = acc;
}

// ---------------------------------------------------------------------------
// Bucket build v2 (two-phase, LDS histogram; proven in r7).
// ---------------------------------------------------------------------------
__global__ void bucket_build(const int* __restrict__ h1x, const int* __restrict__ s1x,
                             int* __restrict__ bcnt, int* __restrict__ bkh,
                             int* __restrict__ bkp) {
    __shared__ int lcnt[FOLD_NR], lbase[FOLD_NR];
    const int tid = threadIdx.x;
    if (tid < FOLD_NR) lcnt[tid] = 0;
    __syncthreads();
    const int i = blockIdx.x * 256 + tid;
    int h = 0, pay = 0, r1 = -1, r2 = -1, p1 = 0, p2 = 0;
    if (i < NITEMS) {
        h = h1x[i];
        int f = i / SS, s = i - f * SS;
        pay = (s * FEAT + f) | (s1x[i] << 31);
#pragma unroll
        for (int r = 0; r < FOLD_NR; r++) {
            int dd = h - r * FOLD_R;
            if (dd < 0) dd += D1;
            if (dd < FOLD_R + 196) {
                int p = atomicAdd(&lcnt[r], 1);
                if (r1 < 0) { r1 = r; p1 = p; }
                else        { r2 = r; p2 = p; }
            }
        }
    }
    __syncthreads();
    if (tid < FOLD_NR) lbase[tid] = atomicAdd(&bcnt[tid], lcnt[tid]);
    __syncthreads();
    if (r1 >= 0) {
        int pos = lbase[r1] + p1;
        if (pos < BCAP) { bkh[r1 * BCAP + pos] = h; bkp[r1 * BCAP + pos] = pay; }
    }
    if (r2 >= 0) {
        int pos = lbase[r2] + p2;
        if (pos < BCAP) { bkh[r2 * BCAP + pos] = h; bkp[r2 * BCAP + pos] = pay; }
    }
}

// ---------------------------------------------------------------------------
// MCB1 stage A v2: block (r, b) scans only bucket r, LDS-privatized scatter +
// FACTOR fold -> afold[b][t] fp32.
// ---------------------------------------------------------------------------
__global__ void sketch_fold2(const float* __restrict__ img_feat, const int* __restrict__ bcnt,
                             const int* __restrict__ bkh, const int* __restrict__ bkp,
                             float* __restrict__ afold) {
    __shared__ float sl[FOLD_R + 196];
    const int r = blockIdx.x;
    const int b = blockIdx.y;
    const int r0 = r * FOLD_R;
    for (int i = threadIdx.x; i < FOLD_R + 196; i += 256) sl[i] = 0.f;
    __syncthreads();
    const int n = min(bcnt[r], BCAP);
    const float* __restrict__ ib = img_feat + (size_t)b * NITEMS;
    for (int j = threadIdx.x; j < n; j += 256) {
        int h = bkh[r * BCAP + j];
        int pay = bkp[r * BCAP + j];
        int d = h - r0;
        if (d < 0) d += D1;
        float v = ib[pay & 0x7FFFFFFF];
        float val = ((unsigned)pay >> 31) ? v : -v;
        atomicAdd(&sl[d], val);
    }
    __syncthreads();
    float* ab = afold + (size_t)b * D1;
    for (int t = threadIdx.x; t < FOLD_R; t += 256) {
        int g = r0 + t;
        if (g >= D1) break;
        ab[g] = sl[t] + sl[t + 49] + sl[t + 98] + sl[t + 147] + sl[t + 196];
    }
}

// ---------------------------------------------------------------------------
// MCB1 stage B v2: transpose afold[b][t] -> A2[dv][u][q].
// ---------------------------------------------------------------------------
__global__ void transpose_f16b(const float* __restrict__ afold, __half2* __restrict__ A2) {
    __shared__ float L[64][65];
    const int t0 = blockIdx.x * 64;
    const int tid = threadIdx.x;
    for (int c = 0; c < 16; c++) {
        int idx = c * 256 + tid;          // b*64 + i
        int b = idx >> 6, i = idx & 63;
        int t = t0 + i;
        L[i][b] = (t < D1) ? afold[(size_t)b * D1 + t] : 0.f;
    }
    __syncthreads();
    for (int c = 0; c < 8; c++) {
        int u8 = c * 256 + tid;           // t_loc*32 + qq
        int t_loc = u8 >> 5, qq = u8 & 31;
        int t = t0 + t_loc;
        if (t >= D1) continue;
        __half2 v = __halves2half2(__float2half_rn(L[t_loc][2 * qq]),
                                   __float2half_rn(L[t_loc][2 * qq + 1]));
        int u = t / 245;
        int dv = t - u * 245;
        A2[((size_t)dv * UPAD + u) * 32 + qq] = v;
        if (u < 8) A2[((size_t)dv * UPAD + 1000 + u) * 32 + qq] = v;   // wrap pad
    }
}

// ---------------------------------------------------------------------------
// Per-s sorted address table (key = (A<<10)|du asc, value = j).
// ---------------------------------------------------------------------------
__global__ void sort_tab(const int* __restrict__ h1q, int2* __restrict__ tab2) {
    __shared__ int k[2048], v[2048];
    const int s = blockIdx.x;
    const int t = threadIdx.x;
#pragma unroll
    for (int e = 0; e < 2; e++) {
        int j = t + e * 1024;
        int d = s - h1q[j];
        if (d < 0) d += D1;
        int du = d / 245;
        int dv = d - du * 245;
        k[j] = ((dv * UPAD + du) << 10) | du;
        v[j] = j;
    }
    for (int size = 2; size <= 2048; size <<= 1) {
        for (int stride = size >> 1; stride > 0; stride >>= 1) {
            __syncthreads();
            int pos = 2 * t - (t & (stride - 1));
            bool asc = ((pos & size) == 0);
            int a = k[pos], b2 = k[pos + stride];
            if ((a > b2) == asc) {
                k[pos] = b2; k[pos + stride] = a;
                int tmp = v[pos]; v[pos] = v[pos + stride]; v[pos + stride] = tmp;
            }
        }
    }
    __syncthreads();
#pragma unroll
    for (int e = 0; e < 2; e++) {
        int r = t + e * 1024;
        tab2[(size_t)s * 2048 + r] = make_int2(k[r], v[r]);
    }
}

// vTs[j][q] = half2( qf[2q][j]*sgn[j], qf[2q+1][j]*sgn[j] )   (natural j order)
__global__ void vts_build(const float* __restrict__ qf, const int* __restrict__ s1q,
                          __half2* __restrict__ vTs) {
    int gid = blockIdx.x * blockDim.x + threadIdx.x;
    if (gid >= 2048 * 32) return;
    int j = gid >> 5, q = gid & 31;
    float sg = (float)(2 * s1q[j] - 1);
    vTs[gid] = __halves2half2(__float2half_rn(qf[(size_t)(2 * q) * 2048 + j] * sg),
                              __float2half_rn(qf[(size_t)(2 * q + 1) * 2048 + j] * sg));
}

// vS[(s*2048+r)*32+q] = vTs[tab2[s*2048+r].y * 32 + q]  (sorted order per s)
__global__ void vs_permute(const __half2* __restrict__ vTs, const int2* __restrict__ tab2,
                           __half2* __restrict__ vS) {
    int gid = blockIdx.x * 256 + threadIdx.x;
    if (gid >= SS * 2048 * 32) return;
    int q = gid & 31;
    int sr = gid >> 5;
    int j = tab2[sr].y;
    vS[gid] = vTs[j * 32 + q];
}

// ---------------------------------------------------------------------------
// MCB1 gather v8 (unroll 2, proven 673 us).  Keys-only LDS table, vS
// pre-permuted, v_fma_mix_f32, pad-17 reduce.
// ---------------------------------------------------------------------------
__global__ void __launch_bounds__(256, 8)
mcb1_gather8(const __half2* __restrict__ A2, const __half2* __restrict__ vS,
             const int2* __restrict__ tab2, float* __restrict__ iq) {
    __shared__ int sp[2176];                       // 8 KB keys (+pad for reduce alias)
    const int wid = blockIdx.x;
    const int lin = (wid & 7) * 196 + (wid >> 3);  // XCD-clustered remap (8*196=1568)
    const int s = lin >> 5;
    const int bx = lin & 31;
    const int tid = threadIdx.x;
    for (int i = tid; i < 2048; i += 256) sp[i] = tab2[(size_t)s * 2048 + i].x;
    __syncthreads();

    const int q = tid & 31;
    const int w = tid >> 5;
    const int mgrp = w & 3;
    const int jh = w >> 2;
    const int m0 = bx * 32 + mgrp * 8;
    const int m0c = (m0 <= 992) ? m0 : 992;        // clamp (block 31 tail)
    const int m0w = m0c - 1000;                    // wrapped variant
    const int thr = 1000 - m0c;                    // du >= thr -> wrap

    float accL[8], accH[8];
#pragma unroll
    for (int kk = 0; kk < 8; kk++) { accL[kk] = 0.f; accH[kk] = 0.f; }

    const unsigned* __restrict__ vp =
        (const unsigned*)vS + (((size_t)s * 2048 + (jh << 10)) << 5) + q;
    const unsigned* __restrict__ abase = (const unsigned*)A2 + q;  // q folded into base
    const int rbase = jh << 10;

#pragma unroll 2
    for (int r = 0; r < 1024; ++r) {
        int key = sp[rbase + r];
        int A = key >> 10;
        int du = key & 1023;
        int t = A + ((du >= thr) ? m0w : m0c);
        const unsigned* __restrict__ arow = abase + ((size_t)t << 5);
        unsigned vv = vp[(size_t)r << 5];
#pragma unroll
        for (int kk = 0; kk < 8; kk++) {
            unsigned a = arow[kk * 32];
            asm("v_fma_mix_f32 %0, %1, %2, %0 op_sel:[0,0,0] op_sel_hi:[1,1,0]"
                : "+v"(accL[kk]) : "v"(a), "v"(vv));
            asm("v_fma_mix_f32 %0, %1, %2, %0 op_sel:[1,1,0] op_sel_hi:[1,1,0]"
                : "+v"(accH[kk]) : "v"(a), "v"(vv));
        }
    }

    __syncthreads();
    float* red = (float*)sp;                       // alias: 128 slots x 17-pad = 8704 B
    const int slot = mgrp * 32 + q;                // 0..127
    if (jh == 1) {
        float* dst = red + slot * 17;
#pragma unroll
        for (int kk = 0; kk < 8; kk++) { dst[kk] = accL[kk]; dst[kk + 8] = accH[kk]; }
    }
    __syncthreads();
    if (jh == 0 && m0 <= 992) {
        const float* srcp = red + slot * 17;
        float* o0 = iq + ((size_t)(2 * q) * SS + s) * MOUT + m0;
        float* o1 = o0 + (size_t)SS * MOUT;
#pragma unroll
        for (int kk = 0; kk < 8; kk++) {
            o0[kk] = accL[kk] + srcp[kk];
            o1[kk] = accH[kk] + srcp[kk + 8];
        }
    }
}

// Generic block size (launch 1024 thr for long rows, 256 for short).
__global__ void ssqrt_l2norm(float* __restrict__ x, int n) {
    __shared__ float red[1024];
    __shared__ float inv_s;
    const int nt = blockDim.x;
    int b = blockIdx.x;
    float* xb = x + (size_t)b * n;
    float ss = 0.f;
    for (int i = threadIdx.x; i < n; i += nt) {
        float v = xb[i];
        float y = (v >= 0.f) ? sqrtf(v) : -sqrtf(-v);
        xb[i] = y;
        ss += y * y;
    }
    red[threadIdx.x] = ss;
    __syncthreads();
    for (int s = nt >> 1; s > 0; s >>= 1) {
        if (threadIdx.x < s) red[threadIdx.x] += red[threadIdx.x + s];
        __syncthreads();
    }
    if (threadIdx.x == 0) inv_s = 1.f / fmaxf(sqrtf(red[0]), 1e-12f);
    __syncthreads();
    float inv = inv_s;
    for (int i = threadIdx.x; i < n; i += nt) xb[i] *= inv;
}

__global__ void ifeat_kernel(const float* __restrict__ iatt, const float* __restrict__ img_feat,
                             float* __restrict__ ifeat) {
    int idx = blockIdx.x * blockDim.x + threadIdx.x;
    if (idx >= BB * 4096) return;
    int b = idx >> 12;
    int gf = idx & 4095;
    int g = gf >> 11;
    int f = gf & 2047;
    float acc = 0.f;
    for (int s = 0; s < SS; s++)
        acc += iatt[((size_t)b * 2 + g) * SS + s] * img_feat[((size_t)b * SS + s) * FEAT + f];
    ifeat[idx] = acc;
}

__global__ void mcb2_scatter(const float* __restrict__ ifeat, const int* __restrict__ h2i,
                             const int* __restrict__ s2i, float* __restrict__ atil2) {
    int tid = blockIdx.x * blockDim.x + threadIdx.x;
    if (tid >= BB * 4096) return;
    int i = tid & 4095;
    int b = tid >> 12;
    float v = ifeat[tid] * (float)(2 * s2i[i] - 1);
    int p = h2i[i];
    float* ab = atil2 + (size_t)b * D2;
#pragma unroll
    for (int f = 0; f < 5; f++) {
        int t = p - f;
        if (t < 0) t += D2;
        atomicAdd(&ab[t], v);
    }
}

__global__ void mcb2_gather(const float* __restrict__ atil2, const float* __restrict__ qf,
                            const int* __restrict__ h2q, const int* __restrict__ s2q,
                            float* __restrict__ z) {
    __shared__ float sa[D2];
    __shared__ int sp[2048];
    __shared__ float sv[2048];
    int b = blockIdx.y;
    for (int i = threadIdx.x; i < D2; i += 256) sa[i] = atil2[(size_t)b * D2 + i];
    const float* qb = qf + (size_t)b * 2048;
    for (int j = threadIdx.x; j < 2048; j += 256) {
        sp[j] = h2q[j];
        sv[j] = qb[j] * (float)(2 * s2q[j] - 1);
    }
    __syncthreads();
    int m = blockIdx.x * 256 + threadIdx.x;
    if (m >= MOUT) return;
    int base = 5 * m + D2;
    float acc = 0.f;
#pragma unroll 4
    for (int j = 0; j < 2048; j++) {
        int addr = base - sp[j];
        if (addr >= D2) addr -= D2;
        acc += sv[j] * sa[addr];
    }
    z[(size_t)b * MOUT + m] = acc;
}

__global__ void softmax_rows(const float* __restrict__ logits, float* __restrict__ out, int n) {
    __shared__ float red[1024];
    const int nt = blockDim.x;
    int b = blockIdx.x;
    const float* xr = logits + (size_t)b * n;
    float* orow = out + (size_t)b * n;
    float mx = -1e30f;
    for (int i = threadIdx.x; i < n; i += nt) mx = fmaxf(mx, xr[i]);
    red[threadIdx.x] = mx;
    __syncthreads();
    for (int s = nt >> 1; s > 0; s >>= 1) {
        if (threadIdx.x < s) red[threadIdx.x] = fmaxf(red[threadIdx.x], red[threadIdx.x + s]);
        __syncthreads();
    }
    mx = red[0];
    __syncthreads();
    float sum = 0.f;
    for (int i = threadIdx.x; i < n; i += nt) sum += expf(xr[i] - mx);
    red[threadIdx.x] = sum;
    __syncthreads();
    for (int s = nt >> 1; s > 0; s >>= 1) {
        if (threadIdx.x < s) red[threadIdx.x] += red[threadIdx.x + s];
        __syncthreads();
    }
    float inv = 1.f / red[0];
    for (int i = threadIdx.x; i < n; i += nt) orow[i] = expf(xr[i] - mx) * inv;
}

extern "C" void kernel_launch(void* const* d_in, const int* in_sizes, int n_in,
                              void* d_out, int out_size, void* d_ws, size_t ws_size,
                              hipStream_t stream) {
    (void)in_sizes; (void)n_in; (void)out_size; (void)ws_size;
    const float* ques = (const float*)d_in[0];
    const float* img  = (const float*)d_in[1];
    const float* W_ih = (const float*)d_in[2];
    const float* W_hh = (const float*)d_in[3];
    const float* b_ih = (const float*)d_in[4];
    const float* b_hh = (const float*)d_in[5];
    const float* Wq1  = (const float*)d_in[6];
    const float* bq1  = (const float*)d_in[7];
    const float* Wq2  = (const float*)d_in[8];
    const float* bq2  = (const float*)d_in[9];
    const float* Wi1  = (const float*)d_in[10];
    const float* bi1  = (const float*)d_in[11];
    const float* Wi2  = (const float*)d_in[12];
    const float* bi2  = (const float*)d_in[13];
    const float* Wp   = (const float*)d_in[14];
    const float* bpc  = (const float*)d_in[15];   // classifier bias
    const int* h1x = (const int*)d_in[16];
    const int* s1x = (const int*)d_in[17];
    const int* h1q = (const int*)d_in[18];
    const int* s1q = (const int*)d_in[19];
    const int* h2i = (const int*)d_in[20];
    const int* s2i = (const int*)d_in[21];
    const int* h2q = (const int*)d_in[22];
    const int* s2q = (const int*)d_in[23];
    float* out = (float*)d_out;

    // Workspace layout (4 B units). Region A (0..15,680,000) time-shared:
    // phase1 {xw,hs,hTa,hTb,cst,qa,qatt,xwT} -> afold -> phase2 smalls + tab2 + vS.
    float* ws = (float*)d_ws;
    float* xw    = ws;                  // 6,815,744
    float* hs    = ws + 6815744;        // 1,703,936
    float* hTa   = ws + 8519680;        // 65,536
    float* hTb   = ws + 8585216;        // 65,536
    float* cst   = ws + 8650752;        // 65,536
    float* qa    = ws + 10224640;       // 851,968
    float* qatt  = ws + 11076608;       // 4,096
    float* xwT   = ws + 11080704;       // 6,815,744 (dead before afold written)
    float* afold = ws;                  // 15,680,000 (written after lstm/qfeat)
    // phase2 smalls (inside region A, alive after transpose consumed afold)
    float* iq     = ws;                 // 3,136,000
    float* ia     = ws + 3136000;       // 1,605,632
    float* iatt   = ws + 4741632;       // 8,192
    float* ifeat  = ws + 4749824;       // 262,144
    float* atil2  = ws + 5011968;       // 320,000
    float* z      = ws + 5331968;       // 64,000
    float* logits = ws + 5395968;       // 192,000 (ends 5,587,968)
    int2*  tab2   = (int2*)(ws + 5600000); // 49*2048 int2 = 200,704 dw (to 5,800,704)
    __half2* vS   = (__half2*)(ws + 6000000); // 49*2048*32 half2 = 3,211,264 dw (to 9,211,264)
    // Region B/C (persistent across phases)
    __half2* A2    = (__half2*)(ws + 15680000);   // 245*1008*32 = 7,902,720 dw
    float* qf      = ws + 15680000 + 7905536;     // 131,072
    __half2* vTs   = (__half2*)(qf + 131072);     // 65,536 dwords
    int* bcnt      = (int*)(ws + 15680000 + 7905536 + 131072 + 65536 + 4096); // 64
    int* bkh       = bcnt + 64;                   // 16*8192 = 131,072
    int* bkp       = bkh + FOLD_NR * BCAP;        // 131,072  (end ~96.2 MB)

    // ---- independent preprocessing ----
    (void)hipMemsetAsync(bcnt, 0, 64 * 4, stream);
    bucket_build<<<(NITEMS + 255) / 256, 256, 0, stream>>>(h1x, s1x, bcnt, bkh, bkp);

    // ---- LSTM ----
    {   // xW[(b*T+t), g] = ques(b,t,:) . W_ih(g,:) + b_ih + b_hh
        dim3 grid(4096 / 64, (BB * TT + 127) / 128);
        gemm_abt<128, 64, 16, 8, 4, false><<<grid, 256, 0, stream>>>(
            ques, W_ih, b_ih, b_hh, xw, BB * TT, 4 * HH, EE, EE, EE, 4 * HH);
    }
    {
        dim3 grid(TT, 64);
        xwt_transpose<<<grid, 256, 0, stream>>>(xw, xwT);
    }
    for (int t = 0; t < TT; t++) {
        float* hout = (t & 1) ? hTb : hTa;
        const float* hin = (t & 1) ? hTa : hTb;   // previous step's hout
        lstm_step5<<<256, 256, 0, stream>>>(xwT, W_hh, (t == 0) ? nullptr : hin,
                                            hout, cst, hs, t);
    }
    // ---- question attention ----
    {   // 64x64 tile -> 208 blocks
        dim3 grid(512 / 64, (TT * BB + 63) / 64);
        gemm_abt<64, 64, 16, 4, 4, true><<<grid, 256, 0, stream>>>(
            hs, Wq1, bq1, nullptr, qa, TT * BB, 512, HH, HH, HH, 512);
    }
    qa2_wave<<<(BB * 2 * TT * 64 + 255) / 256, 256, 0, stream>>>(qa, Wq2, bq2, qatt);
    softmax_wave<<<(BB * 2 * 64 + 255) / 256, 256, 0, stream>>>(qatt, BB * 2, TT);
    qfeat_kernel<<<(BB * 2048) / 256, 256, 0, stream>>>(qatt, hs, qf);
    // ---- MCB1: fold -> transpose(f16, [dv][u][q]) -> sorted-table gather ----
    {
        dim3 grid(FOLD_NR, BB);
        sketch_fold2<<<grid, 256, 0, stream>>>(img, bcnt, bkh, bkp, afold);
    }
    {
        int nblk = (D1 + 63) / 64;
        transpose_f16b<<<nblk, 256, 0, stream>>>(afold, A2);
    }
    // tab2/vS alias region A (afold) -> must come after transpose consumed afold
    sort_tab<<<SS, 1024, 0, stream>>>(h1q, tab2);
    vts_build<<<(2048 * 32) / 256, 256, 0, stream>>>(qf, s1q, vTs);
    vs_permute<<<(SS * 2048 * 32 + 255) / 256, 256, 0, stream>>>(vTs, tab2, vS);
    mcb1_gather8<<<1568, 256, 0, stream>>>(A2, vS, tab2, iq);
    ssqrt_l2norm<<<BB, 1024, 0, stream>>>(iq, MOUT * SS);
    {   // 64x64 tile -> 392 blocks
        dim3 grid(512 / 64, (BB * SS + 63) / 64);
        gemm_abt<64, 64, 16, 4, 4, true><<<grid, 256, 0, stream>>>(
            iq, Wi1, bi1, nullptr, ia, BB * SS, 512, MOUT, MOUT, MOUT, 512);
    }
    ia2_wave<<<(BB * 2 * SS * 64 + 255) / 256, 256, 0, stream>>>(ia, Wi2, bi2, iatt);
    softmax_wave<<<(BB * 2 * 64 + 255) / 256, 256, 0, stream>>>(iatt, BB * 2, SS);
    ifeat_kernel<<<(BB * 4096) / 256, 256, 0, stream>>>(iatt, img, ifeat);
    // ---- MCB2 + classifier ----
    (void)hipMemsetAsync(atil2, 0, (size_t)BB * D2 * 4, stream);
    mcb2_scatter<<<(BB * 4096) / 256, 256, 0, stream>>>(ifeat, h2i, s2i, atil2);
    {
        dim3 grid(4, BB);
        mcb2_gather<<<grid, 256, 0, stream>>>(atil2, qf, h2q, s2q, z);
    }
    ssqrt_l2norm<<<BB, 256, 0, stream>>>(z, MOUT);
    {
        dim3 grid((VOCAB + 63) / 64, 4);
        gemm_abt<16, 64, 16, 2, 2, false><<<grid, 256, 0, stream>>>(
            z, Wp, bpc, nullptr, logits, BB, VOCAB, MOUT, MOUT, MOUT, VOCAB);
    }
    softmax_rows<<<BB, 1024, 0, stream>>>(logits, out, VOCAB);
}

// Round 12
// 2626.965 us; speedup vs baseline: 1.1677x; 1.1677x over previous
//
#include <hip/hip_runtime.h>
#include <hip/hip_fp16.h>
#include <math.h>

// Problem constants
static constexpr int BB = 64, TT = 26, EE = 300, HH = 1024;
static constexpr int FEAT = 2048, SS = 49;
static constexpr int D1 = 245000, D2 = 5000;
static constexpr int MOUT = 1000;
static constexpr int VOCAB = 3000;

static constexpr int UPAD = 1008;                // u-dim padded: 1000 + 8 wrap rows
static constexpr int FOLD_R = 16000;             // v6 proven config
static constexpr int FOLD_NR = 16;
static constexpr int BCAP = 8192;                // bucket capacity (mean 6634)
static constexpr int NITEMS = FEAT * SS;         // 100352

// ---------------------------------------------------------------------------
// Generic fp32 GEMM: C[M,N] = act( A(M,K) * B(N,K)^T + bias1 + bias2 )
// ---------------------------------------------------------------------------
template <int BM, int BN, int BK, int TM, int TN, bool RELU>
__global__ void gemm_abt(const float* __restrict__ A, const float* __restrict__ B,
                         const float* __restrict__ bias1, const float* __restrict__ bias2,
                         float* __restrict__ C,
                         int M, int N, int K, int lda, int ldb, int ldc) {
    constexpr int THREADS = (BM / TM) * (BN / TN);
    __shared__ __align__(16) float As[BK][BM + 4];
    __shared__ __align__(16) float Bs[BK][BN + 4];
    const int tid = threadIdx.x;
    const int tx = tid % (BN / TN);
    const int ty = tid / (BN / TN);
    const int block_m = blockIdx.y * BM;
    const int block_n = blockIdx.x * BN;
    float acc[TM][TN];
#pragma unroll
    for (int i = 0; i < TM; i++)
#pragma unroll
        for (int j = 0; j < TN; j++) acc[i][j] = 0.f;

    for (int k0 = 0; k0 < K; k0 += BK) {
        for (int i = tid; i < BM * BK; i += THREADS) {
            int m = i / BK, kk = i % BK;
            int gm = block_m + m, gk = k0 + kk;
            As[kk][m] = (gm < M && gk < K) ? A[(size_t)gm * lda + gk] : 0.f;
        }
        for (int i = tid; i < BN * BK; i += THREADS) {
            int n = i / BK, kk = i % BK;
            int gn = block_n + n, gk = k0 + kk;
            Bs[kk][n] = (gn < N && gk < K) ? B[(size_t)gn * ldb + gk] : 0.f;
        }
        __syncthreads();
#pragma unroll
        for (int kk = 0; kk < BK; kk++) {
            float a[TM], b[TN];
            if constexpr ((TM & 3) == 0 && (TN & 3) == 0) {
#pragma unroll
                for (int i = 0; i < TM / 4; i++) {
                    float4 t4 = *reinterpret_cast<const float4*>(&As[kk][ty * TM + 4 * i]);
                    a[4 * i] = t4.x; a[4 * i + 1] = t4.y;
                    a[4 * i + 2] = t4.z; a[4 * i + 3] = t4.w;
                }
#pragma unroll
                for (int j = 0; j < TN / 4; j++) {
                    float4 t4 = *reinterpret_cast<const float4*>(&Bs[kk][tx * TN + 4 * j]);
                    b[4 * j] = t4.x; b[4 * j + 1] = t4.y;
                    b[4 * j + 2] = t4.z; b[4 * j + 3] = t4.w;
                }
            } else {
#pragma unroll
                for (int i = 0; i < TM; i++) a[i] = As[kk][ty * TM + i];
#pragma unroll
                for (int j = 0; j < TN; j++) b[j] = Bs[kk][tx * TN + j];
            }
#pragma unroll
            for (int i = 0; i < TM; i++)
#pragma unroll
                for (int j = 0; j < TN; j++) acc[i][j] += a[i] * b[j];
        }
        __syncthreads();
    }
#pragma unroll
    for (int i = 0; i < TM; i++) {
        int gm = block_m + ty * TM + i;
        if (gm >= M) continue;
#pragma unroll
        for (int j = 0; j < TN; j++) {
            int gn = block_n + tx * TN + j;
            if (gn >= N) continue;
            float v = acc[i][j];
            if (bias1) v += bias1[gn];
            if (bias2) v += bias2[gn];
            if (RELU) v = fmaxf(v, 0.f);
            C[(size_t)gm * ldc + gn] = v;
        }
    }
}

// ---------------------------------------------------------------------------
// xw transpose: xw[(b*T+t), g] -> xwT[(t*4096+g)*64 + b]
// ---------------------------------------------------------------------------
__global__ void xwt_transpose(const float* __restrict__ xw, float* __restrict__ xwT) {
    __shared__ float L[64][65];
    const int t = blockIdx.x;
    const int g0 = blockIdx.y * 64;
    const int tid = threadIdx.x;
    for (int u = 0; u < 16; u++) {
        int idx = u * 256 + tid;
        int b = idx >> 6, g = idx & 63;
        L[g][b] = xw[((size_t)b * TT + t) * 4096 + g0 + g];
    }
    __syncthreads();
    for (int u = 0; u < 16; u++) {
        int idx = u * 256 + tid;
        int g = idx >> 6, b = idx & 63;
        xwT[((size_t)t * 4096 + g0 + g) * 64 + b] = L[g][b];
    }
}

// ---------------------------------------------------------------------------
// LSTM per-step kernel v4 (r10 proven best).  Stages W (16 rows x 128 k =
// 8 KB) and h (128 k x 64 b = 32 KB) in double-buffered LDS with float4
// staging + register prefetch.  Thread = (W-row lr, b-quad): per 4 k =
// 1 ds_read_b128 W (16-lane broadcast) + 4 ds_read_b128 h + 16 FMA.
// 256 blocks (4 hidden x 4 gates each) x 256 thr; LDS 80 KB.
// Gate partials exchanged via the W buffer (aliased AFTER final sync).
// ---------------------------------------------------------------------------
__global__ void __launch_bounds__(256, 2)
lstm_step4(const float* __restrict__ xwT, const float* __restrict__ W_hh,
           const float* __restrict__ hin, float* __restrict__ hout,
           float* __restrict__ cst, float* __restrict__ hs, int step) {
    __shared__ __align__(16) float hch[2][128][64];   // 64 KB
    __shared__ __align__(16) float wch[2][16][128];   // 16 KB (part[] aliases later)
    const int tid = threadIdx.x;
    const int hh0 = blockIdx.x * 4;
    float* part = (float*)wch;                        // 16 x 64 floats (4 KB)

    if (step > 0) {
        const int lr = tid >> 4;                      // 0..15 = gate*4 + i
        const int b4 = tid & 15;                      // b quad
        float acc0 = 0.f, acc1 = 0.f, acc2 = 0.f, acc3 = 0.f;
        // stage chunk 0
        {
            const float4* hsrc = (const float4*)hin;
            float4* hdst = (float4*)hch[0];
#pragma unroll
            for (int u = 0; u < 8; u++) hdst[tid + 256 * u] = hsrc[tid + 256 * u];
#pragma unroll
            for (int u = 0; u < 2; u++) {
                int f4 = tid + 256 * u;
                int lr4 = f4 >> 5, c = f4 & 31;
                const float4* wsrc = (const float4*)(
                    W_hh + ((size_t)((lr4 >> 2) * 1024 + hh0 + (lr4 & 3))) * 1024);
                ((float4*)wch[0])[f4] = wsrc[c];
            }
        }
        __syncthreads();
        for (int ck = 0; ck < 8; ck++) {
            const int cur = ck & 1;
            float4 hreg[8];
            float4 wreg[2];
            if (ck < 7) {
                const float4* hsrc = (const float4*)(hin + (ck + 1) * 8192);
#pragma unroll
                for (int u = 0; u < 8; u++) hreg[u] = hsrc[tid + 256 * u];
#pragma unroll
                for (int u = 0; u < 2; u++) {
                    int f4 = tid + 256 * u;
                    int lr4 = f4 >> 5, c = f4 & 31;
                    const float4* wsrc = (const float4*)(
                        W_hh + ((size_t)((lr4 >> 2) * 1024 + hh0 + (lr4 & 3))) * 1024 +
                        (ck + 1) * 128);
                    wreg[u] = wsrc[c];
                }
            }
#pragma unroll 8
            for (int k4 = 0; k4 < 32; k4++) {
                float4 wv = *(const float4*)&wch[cur][lr][k4 * 4];
#pragma unroll
                for (int e = 0; e < 4; e++) {
                    float w = (&wv.x)[e];
                    float4 hv = *(const float4*)&hch[cur][k4 * 4 + e][b4 * 4];
                    acc0 = fmaf(w, hv.x, acc0);
                    acc1 = fmaf(w, hv.y, acc1);
                    acc2 = fmaf(w, hv.z, acc2);
                    acc3 = fmaf(w, hv.w, acc3);
                }
            }
            if (ck < 7) {
                float4* hdst = (float4*)hch[cur ^ 1];
#pragma unroll
                for (int u = 0; u < 8; u++) hdst[tid + 256 * u] = hreg[u];
#pragma unroll
                for (int u = 0; u < 2; u++) ((float4*)wch[cur ^ 1])[tid + 256 * u] = wreg[u];
            }
            __syncthreads();
        }
        // all compute done (post-sync): safe to alias wch as part[]
        part[(lr * 64) + b4 * 4 + 0] = acc0;
        part[(lr * 64) + b4 * 4 + 1] = acc1;
        part[(lr * 64) + b4 * 4 + 2] = acc2;
        part[(lr * 64) + b4 * 4 + 3] = acc3;
        __syncthreads();
    }
    // tail: tid = i*64 + b  (4 hidden x 64 batch = 256 threads exactly)
    {
        const int i = tid >> 6;
        const int b = tid & 63;
        const int row = hh0 + i;
        const int idx = row * 64 + b;
        float g4[4];
#pragma unroll
        for (int j = 0; j < 4; j++) {
            float sum = xwT[((size_t)step * 4096 + j * 1024 + row) * 64 + b];
            if (step > 0) sum += part[(j * 4 + i) * 64 + b];
            g4[j] = sum;
        }
        float si = 1.f / (1.f + expf(-g4[0]));
        float sf = 1.f / (1.f + expf(-g4[1]));
        float tg = tanhf(g4[2]);
        float so = 1.f / (1.f + expf(-g4[3]));
        float cp = (step > 0) ? cst[idx] : 0.f;
        float cn = sf * cp + si * tg;
        cst[idx] = cn;
        float hn = so * tanhf(cn);
        hout[idx] = hn;
        hs[((size_t)step * BB + b) * HH + row] = hn;
    }
}

// Wave-per-row 512-dot: out[r] = dot(arow(r), wrow(g)) + b[g] (r8 proven).
__global__ void qa2_wave(const float* __restrict__ qa, const float* __restrict__ Wq2,
                         const float* __restrict__ bq2, float* __restrict__ out) {
    int wv = (blockIdx.x * blockDim.x + threadIdx.x) >> 6;
    int lane = threadIdx.x & 63;
    if (wv >= BB * 2 * TT) return;
    int t = wv % TT;
    int bg = wv / TT;
    int g = bg & 1;
    const float* arow = qa + ((size_t)t * BB + (bg >> 1)) * 512;
    const float* wrow = Wq2 + g * 512;
    float acc = 0.f;
#pragma unroll
    for (int o = 0; o < 8; o++) acc += wrow[lane + 64 * o] * arow[lane + 64 * o];
    for (int off = 32; off; off >>= 1) acc += __shfl_down(acc, off);
    if (lane == 0) out[wv] = acc + bq2[g];
}

__global__ void ia2_wave(const float* __restrict__ ia, const float* __restrict__ Wi2,
                         const float* __restrict__ bi2, float* __restrict__ out) {
    int wv = (blockIdx.x * blockDim.x + threadIdx.x) >> 6;
    int lane = threadIdx.x & 63;
    if (wv >= BB * 2 * SS) return;
    int s = wv % SS;
    int bg = wv / SS;
    int g = bg & 1;
    const float* arow = ia + ((size_t)(bg >> 1) * SS + s) * 512;
    const float* wrow = Wi2 + g * 512;
    float acc = 0.f;
#pragma unroll
    for (int o = 0; o < 8; o++) acc += wrow[lane + 64 * o] * arow[lane + 64 * o];
    for (int off = 32; off; off >>= 1) acc += __shfl_down(acc, off);
    if (lane == 0) out[wv] = acc + bi2[g];
}

// Wave-per-row softmax, len <= 64.
__global__ void softmax_wave(float* __restrict__ x, int rows, int len) {
    int wv = (blockIdx.x * blockDim.x + threadIdx.x) >> 6;
    int lane = threadIdx.x & 63;
    if (wv >= rows) return;
    float* xr = x + (size_t)wv * len;
    float v = (lane < len) ? xr[lane] : -1e30f;
    float m = v;
    for (int off = 32; off; off >>= 1) m = fmaxf(m, __shfl_xor(m, off));
    float e = (lane < len) ? expf(v - m) : 0.f;
    float ssum = e;
    for (int off = 32; off; off >>= 1) ssum += __shfl_xor(ssum, off);
    if (lane < len) xr[lane] = e / ssum;
}

__global__ void qfeat_kernel(const float* __restrict__ qatt, const float* __restrict__ hs,
                             float* __restrict__ qf) {
    int idx = blockIdx.x * blockDim.x + threadIdx.x;
    if (idx >= BB * 2048) return;
    int b = idx >> 11;
    int gh = idx & 2047;
    int g = gh >> 10;
    int hh = gh & 1023;
    float acc = 0.f;
    for (int t = 0; t < TT; t++)
        acc += qatt[((size_t)b * 2 + g) * TT + t] * hs[((size_t)t * BB + b) * HH + hh];
    qf[idx] = acc;
}

// ---------------------------------------------------------------------------
// Bucket build v2 (two-phase, LDS histogram; proven in r7).
// ---------------------------------------------------------------------------
__global__ void bucket_build(const int* __restrict__ h1x, const int* __restrict__ s1x,
                             int* __restrict__ bcnt, int* __restrict__ bkh,
                             int* __restrict__ bkp) {
    __shared__ int lcnt[FOLD_NR], lbase[FOLD_NR];
    const int tid = threadIdx.x;
    if (tid < FOLD_NR) lcnt[tid] = 0;
    __syncthreads();
    const int i = blockIdx.x * 256 + tid;
    int h = 0, pay = 0, r1 = -1, r2 = -1, p1 = 0, p2 = 0;
    if (i < NITEMS) {
        h = h1x[i];
        int f = i / SS, s = i - f * SS;
        pay = (s * FEAT + f) | (s1x[i] << 31);
#pragma unroll
        for (int r = 0; r < FOLD_NR; r++) {
            int dd = h - r * FOLD_R;
            if (dd < 0) dd += D1;
            if (dd < FOLD_R + 196) {
                int p = atomicAdd(&lcnt[r], 1);
                if (r1 < 0) { r1 = r; p1 = p; }
                else        { r2 = r; p2 = p; }
            }
        }
    }
    __syncthreads();
    if (tid < FOLD_NR) lbase[tid] = atomicAdd(&bcnt[tid], lcnt[tid]);
    __syncthreads();
    if (r1 >= 0) {
        int pos = lbase[r1] + p1;
        if (pos < BCAP) { bkh[r1 * BCAP + pos] = h; bkp[r1 * BCAP + pos] = pay; }
    }
    if (r2 >= 0) {
        int pos = lbase[r2] + p2;
        if (pos < BCAP) { bkh[r2 * BCAP + pos] = h; bkp[r2 * BCAP + pos] = pay; }
    }
}

// ---------------------------------------------------------------------------
// MCB1 stage A v2: block (r, b) scans only bucket r, LDS-privatized scatter +
// FACTOR fold -> afold[b][t] fp32.
// ---------------------------------------------------------------------------
__global__ void sketch_fold2(const float* __restrict__ img_feat, const int* __restrict__ bcnt,
                             const int* __restrict__ bkh, const int* __restrict__ bkp,
                             float* __restrict__ afold) {
    __shared__ float sl[FOLD_R + 196];
    const int r = blockIdx.x;
    const int b = blockIdx.y;
    const int r0 = r * FOLD_R;
    for (int i = threadIdx.x; i < FOLD_R + 196; i += 256) sl[i] = 0.f;
    __syncthreads();
    const int n = min(bcnt[r], BCAP);
    const float* __restrict__ ib = img_feat + (size_t)b * NITEMS;
    for (int j = threadIdx.x; j < n; j += 256) {
        int h = bkh[r * BCAP + j];
        int pay = bkp[r * BCAP + j];
        int d = h - r0;
        if (d < 0) d += D1;
        float v = ib[pay & 0x7FFFFFFF];
        float val = ((unsigned)pay >> 31) ? v : -v;
        atomicAdd(&sl[d], val);
    }
    __syncthreads();
    float* ab = afold + (size_t)b * D1;
    for (int t = threadIdx.x; t < FOLD_R; t += 256) {
        int g = r0 + t;
        if (g >= D1) break;
        ab[g] = sl[t] + sl[t + 49] + sl[t + 98] + sl[t + 147] + sl[t + 196];
    }
}

// ---------------------------------------------------------------------------
// MCB1 stage B v2: transpose afold[b][t] -> A2[dv][u][q].
// ---------------------------------------------------------------------------
__global__ void transpose_f16b(const float* __restrict__ afold, __half2* __restrict__ A2) {
    __shared__ float L[64][65];
    const int t0 = blockIdx.x * 64;
    const int tid = threadIdx.x;
    for (int c = 0; c < 16; c++) {
        int idx = c * 256 + tid;          // b*64 + i
        int b = idx >> 6, i = idx & 63;
        int t = t0 + i;
        L[i][b] = (t < D1) ? afold[(size_t)b * D1 + t] : 0.f;
    }
    __syncthreads();
    for (int c = 0; c < 8; c++) {
        int u8 = c * 256 + tid;           // t_loc*32 + qq
        int t_loc = u8 >> 5, qq = u8 & 31;
        int t = t0 + t_loc;
        if (t >= D1) continue;
        __half2 v = __halves2half2(__float2half_rn(L[t_loc][2 * qq]),
                                   __float2half_rn(L[t_loc][2 * qq + 1]));
        int u = t / 245;
        int dv = t - u * 245;
        A2[((size_t)dv * UPAD + u) * 32 + qq] = v;
        if (u < 8) A2[((size_t)dv * UPAD + 1000 + u) * 32 + qq] = v;   // wrap pad
    }
}

// ---------------------------------------------------------------------------
// Per-s sorted address table (key = (A<<10)|du asc, value = j).
// ---------------------------------------------------------------------------
__global__ void sort_tab(const int* __restrict__ h1q, int2* __restrict__ tab2) {
    __shared__ int k[2048], v[2048];
    const int s = blockIdx.x;
    const int t = threadIdx.x;
#pragma unroll
    for (int e = 0; e < 2; e++) {
        int j = t + e * 1024;
        int d = s - h1q[j];
        if (d < 0) d += D1;
        int du = d / 245;
        int dv = d - du * 245;
        k[j] = ((dv * UPAD + du) << 10) | du;
        v[j] = j;
    }
    for (int size = 2; size <= 2048; size <<= 1) {
        for (int stride = size >> 1; stride > 0; stride >>= 1) {
            __syncthreads();
            int pos = 2 * t - (t & (stride - 1));
            bool asc = ((pos & size) == 0);
            int a = k[pos], b2 = k[pos + stride];
            if ((a > b2) == asc) {
                k[pos] = b2; k[pos + stride] = a;
                int tmp = v[pos]; v[pos] = v[pos + stride]; v[pos + stride] = tmp;
            }
        }
    }
    __syncthreads();
#pragma unroll
    for (int e = 0; e < 2; e++) {
        int r = t + e * 1024;
        tab2[(size_t)s * 2048 + r] = make_int2(k[r], v[r]);
    }
}

// vTs[j][q] = half2( qf[2q][j]*sgn[j], qf[2q+1][j]*sgn[j] )   (natural j order)
__global__ void vts_build(const float* __restrict__ qf, const int* __restrict__ s1q,
                          __half2* __restrict__ vTs) {
    int gid = blockIdx.x * blockDim.x + threadIdx.x;
    if (gid >= 2048 * 32) return;
    int j = gid >> 5, q = gid & 31;
    float sg = (float)(2 * s1q[j] - 1);
    vTs[gid] = __halves2half2(__float2half_rn(qf[(size_t)(2 * q) * 2048 + j] * sg),
                              __float2half_rn(qf[(size_t)(2 * q + 1) * 2048 + j] * sg));
}

// vS[(s*2048+r)*32+q] = vTs[tab2[s*2048+r].y * 32 + q]  (sorted order per s)
__global__ void vs_permute(const __half2* __restrict__ vTs, const int2* __restrict__ tab2,
                           __half2* __restrict__ vS) {
    int gid = blockIdx.x * 256 + threadIdx.x;
    if (gid >= SS * 2048 * 32) return;
    int q = gid & 31;
    int sr = gid >> 5;
    int j = tab2[sr].y;
    vS[gid] = vTs[j * 32 + q];
}

// ---------------------------------------------------------------------------
// MCB1 gather v8 (unroll 2, proven 673 us).  Keys-only LDS table, vS
// pre-permuted, v_fma_mix_f32, pad-17 reduce.
// ---------------------------------------------------------------------------
__global__ void __launch_bounds__(256, 8)
mcb1_gather8(const __half2* __restrict__ A2, const __half2* __restrict__ vS,
             const int2* __restrict__ tab2, float* __restrict__ iq) {
    __shared__ int sp[2176];                       // 8 KB keys (+pad for reduce alias)
    const int wid = blockIdx.x;
    const int lin = (wid & 7) * 196 + (wid >> 3);  // XCD-clustered remap (8*196=1568)
    const int s = lin >> 5;
    const int bx = lin & 31;
    const int tid = threadIdx.x;
    for (int i = tid; i < 2048; i += 256) sp[i] = tab2[(size_t)s * 2048 + i].x;
    __syncthreads();

    const int q = tid & 31;
    const int w = tid >> 5;
    const int mgrp = w & 3;
    const int jh = w >> 2;
    const int m0 = bx * 32 + mgrp * 8;
    const int m0c = (m0 <= 992) ? m0 : 992;        // clamp (block 31 tail)
    const int m0w = m0c - 1000;                    // wrapped variant
    const int thr = 1000 - m0c;                    // du >= thr -> wrap

    float accL[8], accH[8];
#pragma unroll
    for (int kk = 0; kk < 8; kk++) { accL[kk] = 0.f; accH[kk] = 0.f; }

    const unsigned* __restrict__ vp =
        (const unsigned*)vS + (((size_t)s * 2048 + (jh << 10)) << 5) + q;
    const unsigned* __restrict__ abase = (const unsigned*)A2 + q;  // q folded into base
    const int rbase = jh << 10;

#pragma unroll 2
    for (int r = 0; r < 1024; ++r) {
        int key = sp[rbase + r];
        int A = key >> 10;
        int du = key & 1023;
        int t = A + ((du >= thr) ? m0w : m0c);
        const unsigned* __restrict__ arow = abase + ((size_t)t << 5);
        unsigned vv = vp[(size_t)r << 5];
#pragma unroll
        for (int kk = 0; kk < 8; kk++) {
            unsigned a = arow[kk * 32];
            asm("v_fma_mix_f32 %0, %1, %2, %0 op_sel:[0,0,0] op_sel_hi:[1,1,0]"
                : "+v"(accL[kk]) : "v"(a), "v"(vv));
            asm("v_fma_mix_f32 %0, %1, %2, %0 op_sel:[1,1,0] op_sel_hi:[1,1,0]"
                : "+v"(accH[kk]) : "v"(a), "v"(vv));
        }
    }

    __syncthreads();
    float* red = (float*)sp;                       // alias: 128 slots x 17-pad = 8704 B
    const int slot = mgrp * 32 + q;                // 0..127
    if (jh == 1) {
        float* dst = red + slot * 17;
#pragma unroll
        for (int kk = 0; kk < 8; kk++) { dst[kk] = accL[kk]; dst[kk + 8] = accH[kk]; }
    }
    __syncthreads();
    if (jh == 0 && m0 <= 992) {
        const float* srcp = red + slot * 17;
        float* o0 = iq + ((size_t)(2 * q) * SS + s) * MOUT + m0;
        float* o1 = o0 + (size_t)SS * MOUT;
#pragma unroll
        for (int kk = 0; kk < 8; kk++) {
            o0[kk] = accL[kk] + srcp[kk];
            o1[kk] = accH[kk] + srcp[kk + 8];
        }
    }
}

// Generic block size (launch 1024 thr for long rows, 256 for short).
__global__ void ssqrt_l2norm(float* __restrict__ x, int n) {
    __shared__ float red[1024];
    __shared__ float inv_s;
    const int nt = blockDim.x;
    int b = blockIdx.x;
    float* xb = x + (size_t)b * n;
    float ss = 0.f;
    for (int i = threadIdx.x; i < n; i += nt) {
        float v = xb[i];
        float y = (v >= 0.f) ? sqrtf(v) : -sqrtf(-v);
        xb[i] = y;
        ss += y * y;
    }
    red[threadIdx.x] = ss;
    __syncthreads();
    for (int s = nt >> 1; s > 0; s >>= 1) {
        if (threadIdx.x < s) red[threadIdx.x] += red[threadIdx.x + s];
        __syncthreads();
    }
    if (threadIdx.x == 0) inv_s = 1.f / fmaxf(sqrtf(red[0]), 1e-12f);
    __syncthreads();
    float inv = inv_s;
    for (int i = threadIdx.x; i < n; i += nt) xb[i] *= inv;
}

__global__ void ifeat_kernel(const float* __restrict__ iatt, const float* __restrict__ img_feat,
                             float* __restrict__ ifeat) {
    int idx = blockIdx.x * blockDim.x + threadIdx.x;
    if (idx >= BB * 4096) return;
    int b = idx >> 12;
    int gf = idx & 4095;
    int g = gf >> 11;
    int f = gf & 2047;
    float acc = 0.f;
    for (int s = 0; s < SS; s++)
        acc += iatt[((size_t)b * 2 + g) * SS + s] * img_feat[((size_t)b * SS + s) * FEAT + f];
    ifeat[idx] = acc;
}

__global__ void mcb2_scatter(const float* __restrict__ ifeat, const int* __restrict__ h2i,
                             const int* __restrict__ s2i, float* __restrict__ atil2) {
    int tid = blockIdx.x * blockDim.x + threadIdx.x;
    if (tid >= BB * 4096) return;
    int i = tid & 4095;
    int b = tid >> 12;
    float v = ifeat[tid] * (float)(2 * s2i[i] - 1);
    int p = h2i[i];
    float* ab = atil2 + (size_t)b * D2;
#pragma unroll
    for (int f = 0; f < 5; f++) {
        int t = p - f;
        if (t < 0) t += D2;
        atomicAdd(&ab[t], v);
    }
}

__global__ void mcb2_gather(const float* __restrict__ atil2, const float* __restrict__ qf,
                            const int* __restrict__ h2q, const int* __restrict__ s2q,
                            float* __restrict__ z) {
    __shared__ float sa[D2];
    __shared__ int sp[2048];
    __shared__ float sv[2048];
    int b = blockIdx.y;
    for (int i = threadIdx.x; i < D2; i += 256) sa[i] = atil2[(size_t)b * D2 + i];
    const float* qb = qf + (size_t)b * 2048;
    for (int j = threadIdx.x; j < 2048; j += 256) {
        sp[j] = h2q[j];
        sv[j] = qb[j] * (float)(2 * s2q[j] - 1);
    }
    __syncthreads();
    int m = blockIdx.x * 256 + threadIdx.x;
    if (m >= MOUT) return;
    int base = 5 * m + D2;
    float acc = 0.f;
#pragma unroll 4
    for (int j = 0; j < 2048; j++) {
        int addr = base - sp[j];
        if (addr >= D2) addr -= D2;
        acc += sv[j] * sa[addr];
    }
    z[(size_t)b * MOUT + m] = acc;
}

__global__ void softmax_rows(const float* __restrict__ logits, float* __restrict__ out, int n) {
    __shared__ float red[1024];
    const int nt = blockDim.x;
    int b = blockIdx.x;
    const float* xr = logits + (size_t)b * n;
    float* orow = out + (size_t)b * n;
    float mx = -1e30f;
    for (int i = threadIdx.x; i < n; i += nt) mx = fmaxf(mx, xr[i]);
    red[threadIdx.x] = mx;
    __syncthreads();
    for (int s = nt >> 1; s > 0; s >>= 1) {
        if (threadIdx.x < s) red[threadIdx.x] = fmaxf(red[threadIdx.x], red[threadIdx.x + s]);
        __syncthreads();
    }
    mx = red[0];
    __syncthreads();
    float sum = 0.f;
    for (int i = threadIdx.x; i < n; i += nt) sum += expf(xr[i] - mx);
    red[threadIdx.x] = sum;
    __syncthreads();
    for (int s = nt >> 1; s > 0; s >>= 1) {
        if (threadIdx.x < s) red[threadIdx.x] += red[threadIdx.x + s];
        __syncthreads();
    }
    float inv = 1.f / red[0];
    for (int i = threadIdx.x; i < n; i += nt) orow[i] = expf(xr[i] - mx) * inv;
}

extern "C" void kernel_launch(void* const* d_in, const int* in_sizes, int n_in,
                              void* d_out, int out_size, void* d_ws, size_t ws_size,
                              hipStream_t stream) {
    (void)in_sizes; (void)n_in; (void)out_size; (void)ws_size;
    const float* ques = (const float*)d_in[0];
    const float* img  = (const float*)d_in[1];
    const float* W_ih = (const float*)d_in[2];
    const float* W_hh = (const float*)d_in[3];
    const float* b_ih = (const float*)d_in[4];
    const float* b_hh = (const float*)d_in[5];
    const float* Wq1  = (const float*)d_in[6];
    const float* bq1  = (const float*)d_in[7];
    const float* Wq2  = (const float*)d_in[8];
    const float* bq2  = (const float*)d_in[9];
    const float* Wi1  = (const float*)d_in[10];
    const float* bi1  = (const float*)d_in[11];
    const float* Wi2  = (const float*)d_in[12];
    const float* bi2  = (const float*)d_in[13];
    const float* Wp   = (const float*)d_in[14];
    const float* bpc  = (const float*)d_in[15];   // classifier bias
    const int* h1x = (const int*)d_in[16];
    const int* s1x = (const int*)d_in[17];
    const int* h1q = (const int*)d_in[18];
    const int* s1q = (const int*)d_in[19];
    const int* h2i = (const int*)d_in[20];
    const int* s2i = (const int*)d_in[21];
    const int* h2q = (const int*)d_in[22];
    const int* s2q = (const int*)d_in[23];
    float* out = (float*)d_out;

    // Workspace layout (4 B units). Region A (0..15,680,000) time-shared:
    // phase1 {xw,hs,hTa,hTb,cst,qa,qatt,xwT} -> afold -> phase2 smalls + tab2 + vS.
    float* ws = (float*)d_ws;
    float* xw    = ws;                  // 6,815,744
    float* hs    = ws + 6815744;        // 1,703,936
    float* hTa   = ws + 8519680;        // 65,536
    float* hTb   = ws + 8585216;        // 65,536
    float* cst   = ws + 8650752;        // 65,536
    float* qa    = ws + 10224640;       // 851,968
    float* qatt  = ws + 11076608;       // 4,096
    float* xwT   = ws + 11080704;       // 6,815,744 (dead before afold written)
    float* afold = ws;                  // 15,680,000 (written after lstm/qfeat)
    // phase2 smalls (inside region A, alive after transpose consumed afold)
    float* iq     = ws;                 // 3,136,000
    float* ia     = ws + 3136000;       // 1,605,632
    float* iatt   = ws + 4741632;       // 8,192
    float* ifeat  = ws + 4749824;       // 262,144
    float* atil2  = ws + 5011968;       // 320,000
    float* z      = ws + 5331968;       // 64,000
    float* logits = ws + 5395968;       // 192,000 (ends 5,587,968)
    int2*  tab2   = (int2*)(ws + 5600000); // 49*2048 int2 = 200,704 dw (to 5,800,704)
    __half2* vS   = (__half2*)(ws + 6000000); // 49*2048*32 half2 = 3,211,264 dw (to 9,211,264)
    // Region B/C (persistent across phases)
    __half2* A2    = (__half2*)(ws + 15680000);   // 245*1008*32 = 7,902,720 dw
    float* qf      = ws + 15680000 + 7905536;     // 131,072
    __half2* vTs   = (__half2*)(qf + 131072);     // 65,536 dwords
    int* bcnt      = (int*)(ws + 15680000 + 7905536 + 131072 + 65536 + 4096); // 64
    int* bkh       = bcnt + 64;                   // 16*8192 = 131,072
    int* bkp       = bkh + FOLD_NR * BCAP;        // 131,072  (end ~96.2 MB)

    // ---- independent preprocessing ----
    (void)hipMemsetAsync(bcnt, 0, 64 * 4, stream);
    bucket_build<<<(NITEMS + 255) / 256, 256, 0, stream>>>(h1x, s1x, bcnt, bkh, bkp);

    // ---- LSTM ----
    {   // xW[(b*T+t), g] = ques(b,t,:) . W_ih(g,:) + b_ih + b_hh
        dim3 grid(4096 / 64, (BB * TT + 127) / 128);
        gemm_abt<128, 64, 16, 8, 4, false><<<grid, 256, 0, stream>>>(
            ques, W_ih, b_ih, b_hh, xw, BB * TT, 4 * HH, EE, EE, EE, 4 * HH);
    }
    {
        dim3 grid(TT, 64);
        xwt_transpose<<<grid, 256, 0, stream>>>(xw, xwT);
    }
    for (int t = 0; t < TT; t++) {
        float* hout = (t & 1) ? hTb : hTa;
        const float* hin = (t & 1) ? hTa : hTb;   // previous step's hout
        lstm_step4<<<256, 256, 0, stream>>>(xwT, W_hh, (t == 0) ? nullptr : hin,
                                            hout, cst, hs, t);
    }
    // ---- question attention ----
    {   // 64x64 tile -> 208 blocks
        dim3 grid(512 / 64, (TT * BB + 63) / 64);
        gemm_abt<64, 64, 16, 4, 4, true><<<grid, 256, 0, stream>>>(
            hs, Wq1, bq1, nullptr, qa, TT * BB, 512, HH, HH, HH, 512);
    }
    qa2_wave<<<(BB * 2 * TT * 64 + 255) / 256, 256, 0, stream>>>(qa, Wq2, bq2, qatt);
    softmax_wave<<<(BB * 2 * 64 + 255) / 256, 256, 0, stream>>>(qatt, BB * 2, TT);
    qfeat_kernel<<<(BB * 2048) / 256, 256, 0, stream>>>(qatt, hs, qf);
    // ---- MCB1: fold -> transpose(f16, [dv][u][q]) -> sorted-table gather ----
    {
        dim3 grid(FOLD_NR, BB);
        sketch_fold2<<<grid, 256, 0, stream>>>(img, bcnt, bkh, bkp, afold);
    }
    {
        int nblk = (D1 + 63) / 64;
        transpose_f16b<<<nblk, 256, 0, stream>>>(afold, A2);
    }
    // tab2/vS alias region A (afold) -> must come after transpose consumed afold
    sort_tab<<<SS, 1024, 0, stream>>>(h1q, tab2);
    vts_build<<<(2048 * 32) / 256, 256, 0, stream>>>(qf, s1q, vTs);
    vs_permute<<<(SS * 2048 * 32 + 255) / 256, 256, 0, stream>>>(vTs, tab2, vS);
    mcb1_gather8<<<1568, 256, 0, stream>>>(A2, vS, tab2, iq);
    ssqrt_l2norm<<<BB, 1024, 0, stream>>>(iq, MOUT * SS);
    {   // 64x64 tile -> 392 blocks
        dim3 grid(512 / 64, (BB * SS + 63) / 64);
        gemm_abt<64, 64, 16, 4, 4, true><<<grid, 256, 0, stream>>>(
            iq, Wi1, bi1, nullptr, ia, BB * SS, 512, MOUT, MOUT, MOUT, 512);
    }
    ia2_wave<<<(BB * 2 * SS * 64 + 255) / 256, 256, 0, stream>>>(ia, Wi2, bi2, iatt);
    softmax_wave<<<(BB * 2 * 64 + 255) / 256, 256, 0, stream>>>(iatt, BB * 2, SS);
    ifeat_kernel<<<(BB * 4096) / 256, 256, 0, stream>>>(iatt, img, ifeat);
    // ---- MCB2 + classifier ----
    (void)hipMemsetAsync(atil2, 0, (size_t)BB * D2 * 4, stream);
    mcb2_scatter<<<(BB * 4096) / 256, 256, 0, stream>>>(ifeat, h2i, s2i, atil2);
    {
        dim3 grid(4, BB);
        mcb2_gather<<<grid, 256, 0, stream>>>(atil2, qf, h2q, s2q, z);
    }
    ssqrt_l2norm<<<BB, 256, 0, stream>>>(z, MOUT);
    {
        dim3 grid((VOCAB + 63) / 64, 4);
        gemm_abt<16, 64, 16, 2, 2, false><<<grid, 256, 0, stream>>>(
            z, Wp, bpc, nullptr, logits, BB, VOCAB, MOUT, MOUT, MOUT, VOCAB);
    }
    softmax_rows<<<BB, 1024, 0, stream>>>(logits, out, VOCAB);
}

// Round 13
// 2212.412 us; speedup vs baseline: 1.3865x; 1.1874x over previous
//
#include <hip/hip_runtime.h>
#include <hip/hip_fp16.h>
#include <math.h>

// Problem constants
static constexpr int BB = 64, TT = 26, EE = 300, HH = 1024;
static constexpr int FEAT = 2048, SS = 49;
static constexpr int D1 = 245000, D2 = 5000;
static constexpr int MOUT = 1000;
static constexpr int VOCAB = 3000;

static constexpr int UPAD = 1008;                // u-dim padded: 1000 + 8 wrap rows
static constexpr int FOLD_R = 16000;             // v6 proven config
static constexpr int FOLD_NR = 16;
static constexpr int BCAP = 8192;                // bucket capacity (mean 6634)
static constexpr int NITEMS = FEAT * SS;         // 100352

typedef __attribute__((ext_vector_type(8))) _Float16 f16x8;
typedef __attribute__((ext_vector_type(4))) float f32x4;

// ---------------------------------------------------------------------------
// MFMA f16 GEMM: C[M,N] = act( A(M,K) * B(N,K)^T + bias1 + bias2 ).
// Requires M%64==0, N%64==0, K%4==0.  64x64 tile, 4 waves (2x2), each wave
// 32x32 = 2x2 mfma_f32_16x16x32_f16 frags.  f32->f16 conversion in staging.
// A/B frags loaded with IDENTICAL lane->(idx,k) pattern (idx=lane&15,
// k=(lane>>4)*8+e) so any k-permutation error cancels in the contraction;
// C/D layout col=lane&15,row=(lane>>4)*4+reg is HW-verified (guide m89).
// LDS rows padded to 40 halves (80 B) -> frag b128 reads conflict-free.
// ---------------------------------------------------------------------------
template <bool RELU>
__global__ void __launch_bounds__(256, 8)
gemm_mfma(const float* __restrict__ A, const float* __restrict__ B,
          const float* __restrict__ bias1, const float* __restrict__ bias2,
          float* __restrict__ C, int M, int N, int K,
          int lda, int ldb, int ldc) {
    __shared__ __align__(16) _Float16 As[64][40];
    __shared__ __align__(16) _Float16 Bs[64][40];
    const int tid = threadIdx.x;
    const int bm = blockIdx.y * 64, bn = blockIdx.x * 64;
    const int w = tid >> 6, lane = tid & 63;
    const int wr = w >> 1, wc = w & 1;            // wave -> (wr*32, wc*32)
    const int fr = lane & 15, kg = lane >> 4;     // frag index, k-group
    f32x4 acc[2][2];
#pragma unroll
    for (int i = 0; i < 2; i++)
#pragma unroll
        for (int j = 0; j < 2; j++) acc[i][j] = (f32x4){0.f, 0.f, 0.f, 0.f};

    const int r = tid >> 2;                       // staging: row 0..63
    const int kq = (tid & 3) * 8;                 // staging: k-offset 0/8/16/24

    for (int k0 = 0; k0 < K; k0 += 32) {
        // stage A,B (f32 -> f16), zero-fill K tail
        {
            _Float16 ta[8], tb[8];
#pragma unroll
            for (int e4 = 0; e4 < 2; e4++) {
                int gk = k0 + kq + e4 * 4;
                if (gk < K) {                     // K%4==0 -> full float4 valid
                    float4 va = *(const float4*)&A[(size_t)(bm + r) * lda + gk];
                    float4 vb = *(const float4*)&B[(size_t)(bn + r) * ldb + gk];
                    ta[e4*4+0] = (_Float16)va.x; ta[e4*4+1] = (_Float16)va.y;
                    ta[e4*4+2] = (_Float16)va.z; ta[e4*4+3] = (_Float16)va.w;
                    tb[e4*4+0] = (_Float16)vb.x; tb[e4*4+1] = (_Float16)vb.y;
                    tb[e4*4+2] = (_Float16)vb.z; tb[e4*4+3] = (_Float16)vb.w;
                } else {
#pragma unroll
                    for (int e = 0; e < 4; e++) { ta[e4*4+e] = (_Float16)0.f; tb[e4*4+e] = (_Float16)0.f; }
                }
            }
            *(f16x8*)&As[r][kq] = *(f16x8*)ta;
            *(f16x8*)&Bs[r][kq] = *(f16x8*)tb;
        }
        __syncthreads();
        f16x8 af[2], bf[2];
#pragma unroll
        for (int i = 0; i < 2; i++) af[i] = *(const f16x8*)&As[wr * 32 + i * 16 + fr][kg * 8];
#pragma unroll
        for (int j = 0; j < 2; j++) bf[j] = *(const f16x8*)&Bs[wc * 32 + j * 16 + fr][kg * 8];
#pragma unroll
        for (int i = 0; i < 2; i++)
#pragma unroll
            for (int j = 0; j < 2; j++)
                acc[i][j] = __builtin_amdgcn_mfma_f32_16x16x32_f16(af[i], bf[j], acc[i][j], 0, 0, 0);
        __syncthreads();
    }
    // epilogue: row = bm + wr*32 + i*16 + kg*4 + reg, col = bn + wc*32 + j*16 + fr
#pragma unroll
    for (int i = 0; i < 2; i++)
#pragma unroll
        for (int j = 0; j < 2; j++) {
            int col = bn + wc * 32 + j * 16 + fr;
            float bv = 0.f;
            if (bias1) bv += bias1[col];
            if (bias2) bv += bias2[col];
#pragma unroll
            for (int rg = 0; rg < 4; rg++) {
                int row = bm + wr * 32 + i * 16 + kg * 4 + rg;
                float v = acc[i][j][rg] + bv;
                if (RELU) v = fmaxf(v, 0.f);
                C[(size_t)row * ldc + col] = v;
            }
        }
}

// ---------------------------------------------------------------------------
// Generic fp32 GEMM (kept for the odd-shaped classifier).
// ---------------------------------------------------------------------------
template <int BM, int BN, int BK, int TM, int TN, bool RELU>
__global__ void gemm_abt(const float* __restrict__ A, const float* __restrict__ B,
                         const float* __restrict__ bias1, const float* __restrict__ bias2,
                         float* __restrict__ C,
                         int M, int N, int K, int lda, int ldb, int ldc) {
    constexpr int THREADS = (BM / TM) * (BN / TN);
    __shared__ __align__(16) float As[BK][BM + 4];
    __shared__ __align__(16) float Bs[BK][BN + 4];
    const int tid = threadIdx.x;
    const int tx = tid % (BN / TN);
    const int ty = tid / (BN / TN);
    const int block_m = blockIdx.y * BM;
    const int block_n = blockIdx.x * BN;
    float acc[TM][TN];
#pragma unroll
    for (int i = 0; i < TM; i++)
#pragma unroll
        for (int j = 0; j < TN; j++) acc[i][j] = 0.f;

    for (int k0 = 0; k0 < K; k0 += BK) {
        for (int i = tid; i < BM * BK; i += THREADS) {
            int m = i / BK, kk = i % BK;
            int gm = block_m + m, gk = k0 + kk;
            As[kk][m] = (gm < M && gk < K) ? A[(size_t)gm * lda + gk] : 0.f;
        }
        for (int i = tid; i < BN * BK; i += THREADS) {
            int n = i / BK, kk = i % BK;
            int gn = block_n + n, gk = k0 + kk;
            Bs[kk][n] = (gn < N && gk < K) ? B[(size_t)gn * ldb + gk] : 0.f;
        }
        __syncthreads();
#pragma unroll
        for (int kk = 0; kk < BK; kk++) {
            float a[TM], b[TN];
#pragma unroll
            for (int i = 0; i < TM; i++) a[i] = As[kk][ty * TM + i];
#pragma unroll
            for (int j = 0; j < TN; j++) b[j] = Bs[kk][tx * TN + j];
#pragma unroll
            for (int i = 0; i < TM; i++)
#pragma unroll
                for (int j = 0; j < TN; j++) acc[i][j] += a[i] * b[j];
        }
        __syncthreads();
    }
#pragma unroll
    for (int i = 0; i < TM; i++) {
        int gm = block_m + ty * TM + i;
        if (gm >= M) continue;
#pragma unroll
        for (int j = 0; j < TN; j++) {
            int gn = block_n + tx * TN + j;
            if (gn >= N) continue;
            float v = acc[i][j];
            if (bias1) v += bias1[gn];
            if (bias2) v += bias2[gn];
            if (RELU) v = fmaxf(v, 0.f);
            C[(size_t)gm * ldc + gn] = v;
        }
    }
}

// ---------------------------------------------------------------------------
// xw transpose: xw[(b*T+t), g] -> xwT[(t*4096+g)*64 + b]
// ---------------------------------------------------------------------------
__global__ void xwt_transpose(const float* __restrict__ xw, float* __restrict__ xwT) {
    __shared__ float L[64][65];
    const int t = blockIdx.x;
    const int g0 = blockIdx.y * 64;
    const int tid = threadIdx.x;
    for (int u = 0; u < 16; u++) {
        int idx = u * 256 + tid;
        int b = idx >> 6, g = idx & 63;
        L[g][b] = xw[((size_t)b * TT + t) * 4096 + g0 + g];
    }
    __syncthreads();
    for (int u = 0; u < 16; u++) {
        int idx = u * 256 + tid;
        int g = idx >> 6, b = idx & 63;
        xwT[((size_t)t * 4096 + g0 + g) * 64 + b] = L[g][b];
    }
}

// ---------------------------------------------------------------------------
// LSTM per-step kernel v4 (r10/r12 proven best).
// ---------------------------------------------------------------------------
__global__ void __launch_bounds__(256, 2)
lstm_step4(const float* __restrict__ xwT, const float* __restrict__ W_hh,
           const float* __restrict__ hin, float* __restrict__ hout,
           float* __restrict__ cst, float* __restrict__ hs, int step) {
    __shared__ __align__(16) float hch[2][128][64];   // 64 KB
    __shared__ __align__(16) float wch[2][16][128];   // 16 KB (part[] aliases later)
    const int tid = threadIdx.x;
    const int hh0 = blockIdx.x * 4;
    float* part = (float*)wch;                        // 16 x 64 floats (4 KB)

    if (step > 0) {
        const int lr = tid >> 4;                      // 0..15 = gate*4 + i
        const int b4 = tid & 15;                      // b quad
        float acc0 = 0.f, acc1 = 0.f, acc2 = 0.f, acc3 = 0.f;
        {
            const float4* hsrc = (const float4*)hin;
            float4* hdst = (float4*)hch[0];
#pragma unroll
            for (int u = 0; u < 8; u++) hdst[tid + 256 * u] = hsrc[tid + 256 * u];
#pragma unroll
            for (int u = 0; u < 2; u++) {
                int f4 = tid + 256 * u;
                int lr4 = f4 >> 5, c = f4 & 31;
                const float4* wsrc = (const float4*)(
                    W_hh + ((size_t)((lr4 >> 2) * 1024 + hh0 + (lr4 & 3))) * 1024);
                ((float4*)wch[0])[f4] = wsrc[c];
            }
        }
        __syncthreads();
        for (int ck = 0; ck < 8; ck++) {
            const int cur = ck & 1;
            float4 hreg[8];
            float4 wreg[2];
            if (ck < 7) {
                const float4* hsrc = (const float4*)(hin + (ck + 1) * 8192);
#pragma unroll
                for (int u = 0; u < 8; u++) hreg[u] = hsrc[tid + 256 * u];
#pragma unroll
                for (int u = 0; u < 2; u++) {
                    int f4 = tid + 256 * u;
                    int lr4 = f4 >> 5, c = f4 & 31;
                    const float4* wsrc = (const float4*)(
                        W_hh + ((size_t)((lr4 >> 2) * 1024 + hh0 + (lr4 & 3))) * 1024 +
                        (ck + 1) * 128);
                    wreg[u] = wsrc[c];
                }
            }
#pragma unroll 8
            for (int k4 = 0; k4 < 32; k4++) {
                float4 wv = *(const float4*)&wch[cur][lr][k4 * 4];
#pragma unroll
                for (int e = 0; e < 4; e++) {
                    float w = (&wv.x)[e];
                    float4 hv = *(const float4*)&hch[cur][k4 * 4 + e][b4 * 4];
                    acc0 = fmaf(w, hv.x, acc0);
                    acc1 = fmaf(w, hv.y, acc1);
                    acc2 = fmaf(w, hv.z, acc2);
                    acc3 = fmaf(w, hv.w, acc3);
                }
            }
            if (ck < 7) {
                float4* hdst = (float4*)hch[cur ^ 1];
#pragma unroll
                for (int u = 0; u < 8; u++) hdst[tid + 256 * u] = hreg[u];
#pragma unroll
                for (int u = 0; u < 2; u++) ((float4*)wch[cur ^ 1])[tid + 256 * u] = wreg[u];
            }
            __syncthreads();
        }
        part[(lr * 64) + b4 * 4 + 0] = acc0;
        part[(lr * 64) + b4 * 4 + 1] = acc1;
        part[(lr * 64) + b4 * 4 + 2] = acc2;
        part[(lr * 64) + b4 * 4 + 3] = acc3;
        __syncthreads();
    }
    {
        const int i = tid >> 6;
        const int b = tid & 63;
        const int row = hh0 + i;
        const int idx = row * 64 + b;
        float g4[4];
#pragma unroll
        for (int j = 0; j < 4; j++) {
            float sum = xwT[((size_t)step * 4096 + j * 1024 + row) * 64 + b];
            if (step > 0) sum += part[(j * 4 + i) * 64 + b];
            g4[j] = sum;
        }
        float si = 1.f / (1.f + expf(-g4[0]));
        float sf = 1.f / (1.f + expf(-g4[1]));
        float tg = tanhf(g4[2]);
        float so = 1.f / (1.f + expf(-g4[3]));
        float cp = (step > 0) ? cst[idx] : 0.f;
        float cn = sf * cp + si * tg;
        cst[idx] = cn;
        float hn = so * tanhf(cn);
        hout[idx] = hn;
        hs[((size_t)step * BB + b) * HH + row] = hn;
    }
}

// Wave-per-row 512-dot (r8 proven).
__global__ void qa2_wave(const float* __restrict__ qa, const float* __restrict__ Wq2,
                         const float* __restrict__ bq2, float* __restrict__ out) {
    int wv = (blockIdx.x * blockDim.x + threadIdx.x) >> 6;
    int lane = threadIdx.x & 63;
    if (wv >= BB * 2 * TT) return;
    int t = wv % TT;
    int bg = wv / TT;
    int g = bg & 1;
    const float* arow = qa + ((size_t)t * BB + (bg >> 1)) * 512;
    const float* wrow = Wq2 + g * 512;
    float acc = 0.f;
#pragma unroll
    for (int o = 0; o < 8; o++) acc += wrow[lane + 64 * o] * arow[lane + 64 * o];
    for (int off = 32; off; off >>= 1) acc += __shfl_down(acc, off);
    if (lane == 0) out[wv] = acc + bq2[g];
}

__global__ void ia2_wave(const float* __restrict__ ia, const float* __restrict__ Wi2,
                         const float* __restrict__ bi2, float* __restrict__ out) {
    int wv = (blockIdx.x * blockDim.x + threadIdx.x) >> 6;
    int lane = threadIdx.x & 63;
    if (wv >= BB * 2 * SS) return;
    int s = wv % SS;
    int bg = wv / SS;
    int g = bg & 1;
    const float* arow = ia + ((size_t)(bg >> 1) * SS + s) * 512;
    const float* wrow = Wi2 + g * 512;
    float acc = 0.f;
#pragma unroll
    for (int o = 0; o < 8; o++) acc += wrow[lane + 64 * o] * arow[lane + 64 * o];
    for (int off = 32; off; off >>= 1) acc += __shfl_down(acc, off);
    if (lane == 0) out[wv] = acc + bi2[g];
}

// Wave-per-row softmax, len <= 64.
__global__ void softmax_wave(float* __restrict__ x, int rows, int len) {
    int wv = (blockIdx.x * blockDim.x + threadIdx.x) >> 6;
    int lane = threadIdx.x & 63;
    if (wv >= rows) return;
    float* xr = x + (size_t)wv * len;
    float v = (lane < len) ? xr[lane] : -1e30f;
    float m = v;
    for (int off = 32; off; off >>= 1) m = fmaxf(m, __shfl_xor(m, off));
    float e = (lane < len) ? expf(v - m) : 0.f;
    float ssum = e;
    for (int off = 32; off; off >>= 1) ssum += __shfl_xor(ssum, off);
    if (lane < len) xr[lane] = e / ssum;
}

__global__ void qfeat_kernel(const float* __restrict__ qatt, const float* __restrict__ hs,
                             float* __restrict__ qf) {
    int idx = blockIdx.x * blockDim.x + threadIdx.x;
    if (idx >= BB * 2048) return;
    int b = idx >> 11;
    int gh = idx & 2047;
    int g = gh >> 10;
    int hh = gh & 1023;
    float acc = 0.f;
    for (int t = 0; t < TT; t++)
        acc += qatt[((size_t)b * 2 + g) * TT + t] * hs[((size_t)t * BB + b) * HH + hh];
    qf[idx] = acc;
}

// ---------------------------------------------------------------------------
// Bucket build v2 (two-phase, LDS histogram; proven in r7).
// ---------------------------------------------------------------------------
__global__ void bucket_build(const int* __restrict__ h1x, const int* __restrict__ s1x,
                             int* __restrict__ bcnt, int* __restrict__ bkh,
                             int* __restrict__ bkp) {
    __shared__ int lcnt[FOLD_NR], lbase[FOLD_NR];
    const int tid = threadIdx.x;
    if (tid < FOLD_NR) lcnt[tid] = 0;
    __syncthreads();
    const int i = blockIdx.x * 256 + tid;
    int h = 0, pay = 0, r1 = -1, r2 = -1, p1 = 0, p2 = 0;
    if (i < NITEMS) {
        h = h1x[i];
        int f = i / SS, s = i - f * SS;
        pay = (s * FEAT + f) | (s1x[i] << 31);
#pragma unroll
        for (int r = 0; r < FOLD_NR; r++) {
            int dd = h - r * FOLD_R;
            if (dd < 0) dd += D1;
            if (dd < FOLD_R + 196) {
                int p = atomicAdd(&lcnt[r], 1);
                if (r1 < 0) { r1 = r; p1 = p; }
                else        { r2 = r; p2 = p; }
            }
        }
    }
    __syncthreads();
    if (tid < FOLD_NR) lbase[tid] = atomicAdd(&bcnt[tid], lcnt[tid]);
    __syncthreads();
    if (r1 >= 0) {
        int pos = lbase[r1] + p1;
        if (pos < BCAP) { bkh[r1 * BCAP + pos] = h; bkp[r1 * BCAP + pos] = pay; }
    }
    if (r2 >= 0) {
        int pos = lbase[r2] + p2;
        if (pos < BCAP) { bkh[r2 * BCAP + pos] = h; bkp[r2 * BCAP + pos] = pay; }
    }
}

// ---------------------------------------------------------------------------
// MCB1 stage A v2: LDS-privatized scatter + FACTOR fold.
// ---------------------------------------------------------------------------
__global__ void sketch_fold2(const float* __restrict__ img_feat, const int* __restrict__ bcnt,
                             const int* __restrict__ bkh, const int* __restrict__ bkp,
                             float* __restrict__ afold) {
    __shared__ float sl[FOLD_R + 196];
    const int r = blockIdx.x;
    const int b = blockIdx.y;
    const int r0 = r * FOLD_R;
    for (int i = threadIdx.x; i < FOLD_R + 196; i += 256) sl[i] = 0.f;
    __syncthreads();
    const int n = min(bcnt[r], BCAP);
    const float* __restrict__ ib = img_feat + (size_t)b * NITEMS;
    for (int j = threadIdx.x; j < n; j += 256) {
        int h = bkh[r * BCAP + j];
        int pay = bkp[r * BCAP + j];
        int d = h - r0;
        if (d < 0) d += D1;
        float v = ib[pay & 0x7FFFFFFF];
        float val = ((unsigned)pay >> 31) ? v : -v;
        atomicAdd(&sl[d], val);
    }
    __syncthreads();
    float* ab = afold + (size_t)b * D1;
    for (int t = threadIdx.x; t < FOLD_R; t += 256) {
        int g = r0 + t;
        if (g >= D1) break;
        ab[g] = sl[t] + sl[t + 49] + sl[t + 98] + sl[t + 147] + sl[t + 196];
    }
}

// ---------------------------------------------------------------------------
// MCB1 stage B v2: transpose afold[b][t] -> A2[dv][u][q].
// ---------------------------------------------------------------------------
__global__ void transpose_f16b(const float* __restrict__ afold, __half2* __restrict__ A2) {
    __shared__ float L[64][65];
    const int t0 = blockIdx.x * 64;
    const int tid = threadIdx.x;
    for (int c = 0; c < 16; c++) {
        int idx = c * 256 + tid;          // b*64 + i
        int b = idx >> 6, i = idx & 63;
        int t = t0 + i;
        L[i][b] = (t < D1) ? afold[(size_t)b * D1 + t] : 0.f;
    }
    __syncthreads();
    for (int c = 0; c < 8; c++) {
        int u8 = c * 256 + tid;           // t_loc*32 + qq
        int t_loc = u8 >> 5, qq = u8 & 31;
        int t = t0 + t_loc;
        if (t >= D1) continue;
        __half2 v = __halves2half2(__float2half_rn(L[t_loc][2 * qq]),
                                   __float2half_rn(L[t_loc][2 * qq + 1]));
        int u = t / 245;
        int dv = t - u * 245;
        A2[((size_t)dv * UPAD + u) * 32 + qq] = v;
        if (u < 8) A2[((size_t)dv * UPAD + 1000 + u) * 32 + qq] = v;   // wrap pad
    }
}

// ---------------------------------------------------------------------------
// Per-s sorted address table (key = (A<<10)|du asc, value = j).
// ---------------------------------------------------------------------------
__global__ void sort_tab(const int* __restrict__ h1q, int2* __restrict__ tab2) {
    __shared__ int k[2048], v[2048];
    const int s = blockIdx.x;
    const int t = threadIdx.x;
#pragma unroll
    for (int e = 0; e < 2; e++) {
        int j = t + e * 1024;
        int d = s - h1q[j];
        if (d < 0) d += D1;
        int du = d / 245;
        int dv = d - du * 245;
        k[j] = ((dv * UPAD + du) << 10) | du;
        v[j] = j;
    }
    for (int size = 2; size <= 2048; size <<= 1) {
        for (int stride = size >> 1; stride > 0; stride >>= 1) {
            __syncthreads();
            int pos = 2 * t - (t & (stride - 1));
            bool asc = ((pos & size) == 0);
            int a = k[pos], b2 = k[pos + stride];
            if ((a > b2) == asc) {
                k[pos] = b2; k[pos + stride] = a;
                int tmp = v[pos]; v[pos] = v[pos + stride]; v[pos + stride] = tmp;
            }
        }
    }
    __syncthreads();
#pragma unroll
    for (int e = 0; e < 2; e++) {
        int r = t + e * 1024;
        tab2[(size_t)s * 2048 + r] = make_int2(k[r], v[r]);
    }
}

// vTs[j][q] = half2( qf[2q][j]*sgn[j], qf[2q+1][j]*sgn[j] )
__global__ void vts_build(const float* __restrict__ qf, const int* __restrict__ s1q,
                          __half2* __restrict__ vTs) {
    int gid = blockIdx.x * blockDim.x + threadIdx.x;
    if (gid >= 2048 * 32) return;
    int j = gid >> 5, q = gid & 31;
    float sg = (float)(2 * s1q[j] - 1);
    vTs[gid] = __halves2half2(__float2half_rn(qf[(size_t)(2 * q) * 2048 + j] * sg),
                              __float2half_rn(qf[(size_t)(2 * q + 1) * 2048 + j] * sg));
}

// vS[(s*2048+r)*32+q] = vTs[tab2[s*2048+r].y * 32 + q]
__global__ void vs_permute(const __half2* __restrict__ vTs, const int2* __restrict__ tab2,
                           __half2* __restrict__ vS) {
    int gid = blockIdx.x * 256 + threadIdx.x;
    if (gid >= SS * 2048 * 32) return;
    int q = gid & 31;
    int sr = gid >> 5;
    int j = tab2[sr].y;
    vS[gid] = vTs[j * 32 + q];
}

// ---------------------------------------------------------------------------
// MCB1 gather v8 (unroll 2, proven ~665 us).
// ---------------------------------------------------------------------------
__global__ void __launch_bounds__(256, 8)
mcb1_gather8(const __half2* __restrict__ A2, const __half2* __restrict__ vS,
             const int2* __restrict__ tab2, float* __restrict__ iq) {
    __shared__ int sp[2176];                       // 8 KB keys (+pad for reduce alias)
    const int wid = blockIdx.x;
    const int lin = (wid & 7) * 196 + (wid >> 3);  // XCD-clustered remap (8*196=1568)
    const int s = lin >> 5;
    const int bx = lin & 31;
    const int tid = threadIdx.x;
    for (int i = tid; i < 2048; i += 256) sp[i] = tab2[(size_t)s * 2048 + i].x;
    __syncthreads();

    const int q = tid & 31;
    const int w = tid >> 5;
    const int mgrp = w & 3;
    const int jh = w >> 2;
    const int m0 = bx * 32 + mgrp * 8;
    const int m0c = (m0 <= 992) ? m0 : 992;        // clamp (block 31 tail)
    const int m0w = m0c - 1000;                    // wrapped variant
    const int thr = 1000 - m0c;                    // du >= thr -> wrap

    float accL[8], accH[8];
#pragma unroll
    for (int kk = 0; kk < 8; kk++) { accL[kk] = 0.f; accH[kk] = 0.f; }

    const unsigned* __restrict__ vp =
        (const unsigned*)vS + (((size_t)s * 2048 + (jh << 10)) << 5) + q;
    const unsigned* __restrict__ abase = (const unsigned*)A2 + q;  // q folded into base
    const int rbase = jh << 10;

#pragma unroll 2
    for (int r = 0; r < 1024; ++r) {
        int key = sp[rbase + r];
        int A = key >> 10;
        int du = key & 1023;
        int t = A + ((du >= thr) ? m0w : m0c);
        const unsigned* __restrict__ arow = abase + ((size_t)t << 5);
        unsigned vv = vp[(size_t)r << 5];
#pragma unroll
        for (int kk = 0; kk < 8; kk++) {
            unsigned a = arow[kk * 32];
            asm("v_fma_mix_f32 %0, %1, %2, %0 op_sel:[0,0,0] op_sel_hi:[1,1,0]"
                : "+v"(accL[kk]) : "v"(a), "v"(vv));
            asm("v_fma_mix_f32 %0, %1, %2, %0 op_sel:[1,1,0] op_sel_hi:[1,1,0]"
                : "+v"(accH[kk]) : "v"(a), "v"(vv));
        }
    }

    __syncthreads();
    float* red = (float*)sp;                       // alias: 128 slots x 17-pad = 8704 B
    const int slot = mgrp * 32 + q;                // 0..127
    if (jh == 1) {
        float* dst = red + slot * 17;
#pragma unroll
        for (int kk = 0; kk < 8; kk++) { dst[kk] = accL[kk]; dst[kk + 8] = accH[kk]; }
    }
    __syncthreads();
    if (jh == 0 && m0 <= 992) {
        const float* srcp = red + slot * 17;
        float* o0 = iq + ((size_t)(2 * q) * SS + s) * MOUT + m0;
        float* o1 = o0 + (size_t)SS * MOUT;
#pragma unroll
        for (int kk = 0; kk < 8; kk++) {
            o0[kk] = accL[kk] + srcp[kk];
            o1[kk] = accH[kk] + srcp[kk + 8];
        }
    }
}

// Generic block size (launch 1024 thr for long rows, 256 for short).
__global__ void ssqrt_l2norm(float* __restrict__ x, int n) {
    __shared__ float red[1024];
    __shared__ float inv_s;
    const int nt = blockDim.x;
    int b = blockIdx.x;
    float* xb = x + (size_t)b * n;
    float ss = 0.f;
    for (int i = threadIdx.x; i < n; i += nt) {
        float v = xb[i];
        float y = (v >= 0.f) ? sqrtf(v) : -sqrtf(-v);
        xb[i] = y;
        ss += y * y;
    }
    red[threadIdx.x] = ss;
    __syncthreads();
    for (int s = nt >> 1; s > 0; s >>= 1) {
        if (threadIdx.x < s) red[threadIdx.x] += red[threadIdx.x + s];
        __syncthreads();
    }
    if (threadIdx.x == 0) inv_s = 1.f / fmaxf(sqrtf(red[0]), 1e-12f);
    __syncthreads();
    float inv = inv_s;
    for (int i = threadIdx.x; i < n; i += nt) xb[i] *= inv;
}

__global__ void ifeat_kernel(const float* __restrict__ iatt, const float* __restrict__ img_feat,
                             float* __restrict__ ifeat) {
    int idx = blockIdx.x * blockDim.x + threadIdx.x;
    if (idx >= BB * 4096) return;
    int b = idx >> 12;
    int gf = idx & 4095;
    int g = gf >> 11;
    int f = gf & 2047;
    float acc = 0.f;
    for (int s = 0; s < SS; s++)
        acc += iatt[((size_t)b * 2 + g) * SS + s] * img_feat[((size_t)b * SS + s) * FEAT + f];
    ifeat[idx] = acc;
}

__global__ void mcb2_scatter(const float* __restrict__ ifeat, const int* __restrict__ h2i,
                             const int* __restrict__ s2i, float* __restrict__ atil2) {
    int tid = blockIdx.x * blockDim.x + threadIdx.x;
    if (tid >= BB * 4096) return;
    int i = tid & 4095;
    int b = tid >> 12;
    float v = ifeat[tid] * (float)(2 * s2i[i] - 1);
    int p = h2i[i];
    float* ab = atil2 + (size_t)b * D2;
#pragma unroll
    for (int f = 0; f < 5; f++) {
        int t = p - f;
        if (t < 0) t += D2;
        atomicAdd(&ab[t], v);
    }
}

__global__ void mcb2_gather(const float* __restrict__ atil2, const float* __restrict__ qf,
                            const int* __restrict__ h2q, const int* __restrict__ s2q,
                            float* __restrict__ z) {
    __shared__ float sa[D2];
    __shared__ int sp[2048];
    __shared__ float sv[2048];
    int b = blockIdx.y;
    for (int i = threadIdx.x; i < D2; i += 256) sa[i] = atil2[(size_t)b * D2 + i];
    const float* qb = qf + (size_t)b * 2048;
    for (int j = threadIdx.x; j < 2048; j += 256) {
        sp[j] = h2q[j];
        sv[j] = qb[j] * (float)(2 * s2q[j] - 1);
    }
    __syncthreads();
    int m = blockIdx.x * 256 + threadIdx.x;
    if (m >= MOUT) return;
    int base = 5 * m + D2;
    float acc = 0.f;
#pragma unroll 4
    for (int j = 0; j < 2048; j++) {
        int addr = base - sp[j];
        if (addr >= D2) addr -= D2;
        acc += sv[j] * sa[addr];
    }
    z[(size_t)b * MOUT + m] = acc;
}

__global__ void softmax_rows(const float* __restrict__ logits, float* __restrict__ out, int n) {
    __shared__ float red[1024];
    const int nt = blockDim.x;
    int b = blockIdx.x;
    const float* xr = logits + (size_t)b * n;
    float* orow = out + (size_t)b * n;
    float mx = -1e30f;
    for (int i = threadIdx.x; i < n; i += nt) mx = fmaxf(mx, xr[i]);
    red[threadIdx.x] = mx;
    __syncthreads();
    for (int s = nt >> 1; s > 0; s >>= 1) {
        if (threadIdx.x < s) red[threadIdx.x] = fmaxf(red[threadIdx.x], red[threadIdx.x + s]);
        __syncthreads();
    }
    mx = red[0];
    __syncthreads();
    float sum = 0.f;
    for (int i = threadIdx.x; i < n; i += nt) sum += expf(xr[i] - mx);
    red[threadIdx.x] = sum;
    __syncthreads();
    for (int s = nt >> 1; s > 0; s >>= 1) {
        if (threadIdx.x < s) red[threadIdx.x] += red[threadIdx.x + s];
        __syncthreads();
    }
    float inv = 1.f / red[0];
    for (int i = threadIdx.x; i < n; i += nt) orow[i] = expf(xr[i] - mx) * inv;
}

extern "C" void kernel_launch(void* const* d_in, const int* in_sizes, int n_in,
                              void* d_out, int out_size, void* d_ws, size_t ws_size,
                              hipStream_t stream) {
    (void)in_sizes; (void)n_in; (void)out_size; (void)ws_size;
    const float* ques = (const float*)d_in[0];
    const float* img  = (const float*)d_in[1];
    const float* W_ih = (const float*)d_in[2];
    const float* W_hh = (const float*)d_in[3];
    const float* b_ih = (const float*)d_in[4];
    const float* b_hh = (const float*)d_in[5];
    const float* Wq1  = (const float*)d_in[6];
    const float* bq1  = (const float*)d_in[7];
    const float* Wq2  = (const float*)d_in[8];
    const float* bq2  = (const float*)d_in[9];
    const float* Wi1  = (const float*)d_in[10];
    const float* bi1  = (const float*)d_in[11];
    const float* Wi2  = (const float*)d_in[12];
    const float* bi2  = (const float*)d_in[13];
    const float* Wp   = (const float*)d_in[14];
    const float* bpc  = (const float*)d_in[15];   // classifier bias
    const int* h1x = (const int*)d_in[16];
    const int* s1x = (const int*)d_in[17];
    const int* h1q = (const int*)d_in[18];
    const int* s1q = (const int*)d_in[19];
    const int* h2i = (const int*)d_in[20];
    const int* s2i = (const int*)d_in[21];
    const int* h2q = (const int*)d_in[22];
    const int* s2q = (const int*)d_in[23];
    float* out = (float*)d_out;

    // Workspace layout (4 B units). Region A (0..15,680,000) time-shared.
    float* ws = (float*)d_ws;
    float* xw    = ws;                  // 6,815,744
    float* hs    = ws + 6815744;        // 1,703,936
    float* hTa   = ws + 8519680;        // 65,536
    float* hTb   = ws + 8585216;        // 65,536
    float* cst   = ws + 8650752;        // 65,536
    float* qa    = ws + 10224640;       // 851,968
    float* qatt  = ws + 11076608;       // 4,096
    float* xwT   = ws + 11080704;       // 6,815,744 (dead before afold written)
    float* afold = ws;                  // 15,680,000 (written after lstm/qfeat)
    // phase2 smalls (inside region A, alive after transpose consumed afold)
    float* iq     = ws;                 // 3,136,000
    float* ia     = ws + 3136000;       // 1,605,632
    float* iatt   = ws + 4741632;       // 8,192
    float* ifeat  = ws + 4749824;       // 262,144
    float* atil2  = ws + 5011968;       // 320,000
    float* z      = ws + 5331968;       // 64,000
    float* logits = ws + 5395968;       // 192,000 (ends 5,587,968)
    int2*  tab2   = (int2*)(ws + 5600000); // 49*2048 int2 = 200,704 dw (to 5,800,704)
    __half2* vS   = (__half2*)(ws + 6000000); // 49*2048*32 half2 = 3,211,264 dw (to 9,211,264)
    // Region B/C (persistent across phases)
    __half2* A2    = (__half2*)(ws + 15680000);   // 245*1008*32 = 7,902,720 dw
    float* qf      = ws + 15680000 + 7905536;     // 131,072
    __half2* vTs   = (__half2*)(qf + 131072);     // 65,536 dwords
    int* bcnt      = (int*)(ws + 15680000 + 7905536 + 131072 + 65536 + 4096); // 64
    int* bkh       = bcnt + 64;                   // 16*8192 = 131,072
    int* bkp       = bkh + FOLD_NR * BCAP;        // 131,072  (end ~96.2 MB)

    // ---- independent preprocessing ----
    (void)hipMemsetAsync(bcnt, 0, 64 * 4, stream);
    bucket_build<<<(NITEMS + 255) / 256, 256, 0, stream>>>(h1x, s1x, bcnt, bkh, bkp);

    // ---- LSTM ----
    {   // xW = ques . W_ih^T + b_ih + b_hh   (MFMA f16: M=1664, N=4096, K=300)
        dim3 grid(4096 / 64, 1664 / 64);
        gemm_mfma<false><<<grid, 256, 0, stream>>>(
            ques, W_ih, b_ih, b_hh, xw, BB * TT, 4 * HH, EE, EE, EE, 4 * HH);
    }
    {
        dim3 grid(TT, 64);
        xwt_transpose<<<grid, 256, 0, stream>>>(xw, xwT);
    }
    for (int t = 0; t < TT; t++) {
        float* hout = (t & 1) ? hTb : hTa;
        const float* hin = (t & 1) ? hTa : hTb;   // previous step's hout
        lstm_step4<<<256, 256, 0, stream>>>(xwT, W_hh, (t == 0) ? nullptr : hin,
                                            hout, cst, hs, t);
    }
    // ---- question attention ----
    {   // qa = relu(hs . Wq1^T + bq1)  (MFMA f16: M=1664, N=512, K=1024)
        dim3 grid(512 / 64, 1664 / 64);
        gemm_mfma<true><<<grid, 256, 0, stream>>>(
            hs, Wq1, bq1, nullptr, qa, TT * BB, 512, HH, HH, HH, 512);
    }
    qa2_wave<<<(BB * 2 * TT * 64 + 255) / 256, 256, 0, stream>>>(qa, Wq2, bq2, qatt);
    softmax_wave<<<(BB * 2 * 64 + 255) / 256, 256, 0, stream>>>(qatt, BB * 2, TT);
    qfeat_kernel<<<(BB * 2048) / 256, 256, 0, stream>>>(qatt, hs, qf);
    // ---- MCB1: fold -> transpose(f16, [dv][u][q]) -> sorted-table gather ----
    {
        dim3 grid(FOLD_NR, BB);
        sketch_fold2<<<grid, 256, 0, stream>>>(img, bcnt, bkh, bkp, afold);
    }
    {
        int nblk = (D1 + 63) / 64;
        transpose_f16b<<<nblk, 256, 0, stream>>>(afold, A2);
    }
    // tab2/vS alias region A (afold) -> must come after transpose consumed afold
    sort_tab<<<SS, 1024, 0, stream>>>(h1q, tab2);
    vts_build<<<(2048 * 32) / 256, 256, 0, stream>>>(qf, s1q, vTs);
    vs_permute<<<(SS * 2048 * 32 + 255) / 256, 256, 0, stream>>>(vTs, tab2, vS);
    mcb1_gather8<<<1568, 256, 0, stream>>>(A2, vS, tab2, iq);
    ssqrt_l2norm<<<BB, 1024, 0, stream>>>(iq, MOUT * SS);
    {   // ia = relu(iq . Wi1^T + bi1)  (MFMA f16: M=3136, N=512, K=1000)
        dim3 grid(512 / 64, 3136 / 64);
        gemm_mfma<true><<<grid, 256, 0, stream>>>(
            iq, Wi1, bi1, nullptr, ia, BB * SS, 512, MOUT, MOUT, MOUT, 512);
    }
    ia2_wave<<<(BB * 2 * SS * 64 + 255) / 256, 256, 0, stream>>>(ia, Wi2, bi2, iatt);
    softmax_wave<<<(BB * 2 * 64 + 255) / 256, 256, 0, stream>>>(iatt, BB * 2, SS);
    ifeat_kernel<<<(BB * 4096) / 256, 256, 0, stream>>>(iatt, img, ifeat);
    // ---- MCB2 + classifier ----
    (void)hipMemsetAsync(atil2, 0, (size_t)BB * D2 * 4, stream);
    mcb2_scatter<<<(BB * 4096) / 256, 256, 0, stream>>>(ifeat, h2i, s2i, atil2);
    {
        dim3 grid(4, BB);
        mcb2_gather<<<grid, 256, 0, stream>>>(atil2, qf, h2q, s2q, z);
    }
    ssqrt_l2norm<<<BB, 256, 0, stream>>>(z, MOUT);
    {
        dim3 grid((VOCAB + 63) / 64, 4);
        gemm_abt<16, 64, 16, 2, 2, false><<<grid, 256, 0, stream>>>(
            z, Wp, bpc, nullptr, logits, BB, VOCAB, MOUT, MOUT, MOUT, VOCAB);
    }
    softmax_rows<<<BB, 1024, 0, stream>>>(logits, out, VOCAB);
}